// Round 6
// baseline (299.471 us; speedup 1.0000x reference)
//
#include <hip/hip_runtime.h>
#include <math.h>

typedef _Float16 f16x8 __attribute__((ext_vector_type(8)));
typedef float f32x4 __attribute__((ext_vector_type(4)));

#define SEQ 2048
#define DM 1024
#define NH 16
#define HD 64
#define MTOT 4096   // batch*seq

#define NEG_BIG (-30000.0f)

// ---------------------------------------------------------------------------
// fp32 -> fp16 straight convert (x): n multiple of 2048.
// ---------------------------------------------------------------------------
__global__ __launch_bounds__(256) void convert_x(const float* __restrict__ src,
                                                 _Float16* __restrict__ dst) {
  const int i = (blockIdx.x * 256 + threadIdx.x) * 8;
  f32x4 a = *(const f32x4*)(src + i);
  f32x4 b = *(const f32x4*)(src + i + 4);
  f16x8 o;
#pragma unroll
  for (int j = 0; j < 4; ++j) { o[j] = (_Float16)a[j]; o[4 + j] = (_Float16)b[j]; }
  *(f16x8*)(dst + i) = o;
}

// ---------------------------------------------------------------------------
// Weight transpose+convert: w fp32 [k][n] (1024x1024) -> wT fp16 [n][k].
// ---------------------------------------------------------------------------
__global__ __launch_bounds__(256) void transpose_w(const float* __restrict__ q,
                                                   const float* __restrict__ k,
                                                   const float* __restrict__ v,
                                                   const float* __restrict__ o,
                                                   _Float16* __restrict__ dstBase) {
  __shared__ float Ts[64][65];
  const float* srcs[4] = {q, k, v, o};
  const float* src = srcs[blockIdx.z];
  _Float16* dst = dstBase + (size_t)blockIdx.z * DM * DM;
  const int t = threadIdx.x;
  const int k0 = blockIdx.y * 64, n0 = blockIdx.x * 64;
  const int r = t >> 2, c4 = (t & 3) * 16;
  const float* sp = src + (size_t)(k0 + r) * DM + n0 + c4;
#pragma unroll
  for (int j = 0; j < 4; ++j) {
    f32x4 vv = *(const f32x4*)(sp + j * 4);
#pragma unroll
    for (int e = 0; e < 4; ++e) Ts[r][c4 + j * 4 + e] = vv[e];
  }
  __syncthreads();
  f16x8 o0, o1;
#pragma unroll
  for (int j = 0; j < 8; ++j) {
    o0[j] = (_Float16)Ts[c4 + j][r];
    o1[j] = (_Float16)Ts[c4 + 8 + j][r];
  }
  _Float16* dp = dst + (size_t)(n0 + r) * DM + k0 + c4;
  *(f16x8*)(dp) = o0;
  *(f16x8*)(dp + 8) = o1;
}

// ---------------------------------------------------------------------------
// GEMM: Y = A(M,K) @ BT^T, BT fp16 [n][k]. 128x128 tile, 4 waves each 64x64.
// FUSED3: BT = 3 concatenated mats (Q,K,V). ROPE: apply RoPE in epilogue to
// mats 0,1 — pair (2d2,2d2+1) = lanes (fl, fl^1): one shfl_xor + sincos.
// ---------------------------------------------------------------------------
template <bool FUSED3, bool OUTF32, bool ROPE>
__global__ __launch_bounds__(256) void gemm128(const _Float16* __restrict__ A,
                                               const _Float16* __restrict__ BT,
                                               void* __restrict__ Yv,
                                               int M, int K) {
  __shared__ _Float16 As[128][40];
  __shared__ _Float16 Bs[128][40];
  const int tid = threadIdx.x;
  const int lane = tid & 63;
  const int fl = lane & 15, fh = lane >> 4;
  const int wave = tid >> 6;
  const int m0 = blockIdx.y * 128;
  int n0 = blockIdx.x * 128;
  int mat = 0;
  const _Float16* Bp = BT;
  char* Yp = (char*)Yv;
  if (FUSED3) {
    mat = n0 >> 10;
    n0 &= 1023;
    Bp = BT + (size_t)mat * DM * DM;
    Yp += (size_t)mat * M * DM * (OUTF32 ? 4 : 2);
  }
  const int wm = (wave >> 1) * 64, wn = (wave & 1) * 64;
  const int sr = tid >> 2, sc = (tid & 3) * 8;

  f32x4 acc[4][4] = {};

  for (int k0 = 0; k0 < K; k0 += 32) {
    f16x8 a0 = *(const f16x8*)(A + (size_t)(m0 + sr) * K + k0 + sc);
    f16x8 a1 = *(const f16x8*)(A + (size_t)(m0 + 64 + sr) * K + k0 + sc);
    f16x8 b0 = *(const f16x8*)(Bp + (size_t)(n0 + sr) * K + k0 + sc);
    f16x8 b1 = *(const f16x8*)(Bp + (size_t)(n0 + 64 + sr) * K + k0 + sc);
    __syncthreads();
    *(f16x8*)(&As[sr][sc]) = a0;
    *(f16x8*)(&As[64 + sr][sc]) = a1;
    *(f16x8*)(&Bs[sr][sc]) = b0;
    *(f16x8*)(&Bs[64 + sr][sc]) = b1;
    __syncthreads();
    f16x8 af[4], bf[4];
#pragma unroll
    for (int mi = 0; mi < 4; ++mi)
      af[mi] = *(const f16x8*)(&As[wm + mi * 16 + fl][fh * 8]);
#pragma unroll
    for (int ni = 0; ni < 4; ++ni)
      bf[ni] = *(const f16x8*)(&Bs[wn + ni * 16 + fl][fh * 8]);
#pragma unroll
    for (int mi = 0; mi < 4; ++mi)
#pragma unroll
      for (int ni = 0; ni < 4; ++ni)
        acc[mi][ni] = __builtin_amdgcn_mfma_f32_16x16x32_f16(af[mi], bf[ni], acc[mi][ni], 0, 0, 0);
  }

  // C/D: row = fh*4 + r, col = fl
#pragma unroll
  for (int mi = 0; mi < 4; ++mi)
#pragma unroll
    for (int ni = 0; ni < 4; ++ni) {
      const int gm = m0 + wm + mi * 16 + fh * 4;
      const int gn = n0 + wn + ni * 16 + fl;
      if (ROPE && mat < 2) {
        const int d2 = (gn & 63) >> 1;
        const float inv = __powf(10000.0f, -(float)d2 * (1.0f / 32.0f));
        const float sgn = (gn & 1) ? 1.0f : -1.0f;
#pragma unroll
        for (int r = 0; r < 4; ++r) {
          const int s = (gm + r) & (SEQ - 1);
          float c, sn;
          __sincosf((float)s * inv, &sn, &c);
          const float v = acc[mi][ni][r];
          const float p = __shfl_xor(v, 1, 64);
          acc[mi][ni][r] = v * c + sgn * p * sn;
        }
      }
#pragma unroll
      for (int r = 0; r < 4; ++r) {
        if (OUTF32)
          ((float*)Yp)[(size_t)(gm + r) * DM + gn] = acc[mi][ni][r];
        else
          ((_Float16*)Yp)[(size_t)(gm + r) * DM + gn] = (_Float16)acc[mi][ni][r];
      }
    }
}

// ---------------------------------------------------------------------------
// Flash attention, causal. Block = 256 thr = 4 waves; block covers 64 q rows
// (16 per wave); KV chunks of 64 staged block-wide (K rows, V transposed).
// LDS 27.6 KB -> 5 blocks/CU LDS-limit; grid 1024 blocks = 4/CU.
// ---------------------------------------------------------------------------
__global__ __launch_bounds__(256) void attn_kernel(const _Float16* __restrict__ Q,
                                                   const _Float16* __restrict__ K,
                                                   const _Float16* __restrict__ V,
                                                   _Float16* __restrict__ O) {
  __shared__ _Float16 Ks[64][72];      // [kv][d]
  __shared__ _Float16 Vt[64][72];      // [d][kv]
  __shared__ _Float16 Pl[4][16][72];   // per-wave P [q][kv]

  const int tid = threadIdx.x;
  const int lane = tid & 63;
  const int fl = lane & 15, fh = lane >> 4;
  const int wave = tid >> 6;
  const int bh = blockIdx.y;
  const int b = bh >> 4, h = bh & 15;
  const int q0 = blockIdx.x * 64;
  const int qt = q0 + wave * 16;

  const _Float16* Qb = Q + (size_t)b * SEQ * DM + h * HD;
  const _Float16* Kb = K + (size_t)b * SEQ * DM + h * HD;
  const _Float16* Vb = V + (size_t)b * SEQ * DM + h * HD;

  f16x8 qf[2];
#pragma unroll
  for (int kh = 0; kh < 2; ++kh)
    qf[kh] = *(const f16x8*)(Qb + (size_t)(qt + fl) * DM + kh * 32 + fh * 8);

  f32x4 o_acc[4] = {};
  float m_r[4], l_r[4];
#pragma unroll
  for (int r = 0; r < 4; ++r) { m_r[r] = NEG_BIG; l_r[r] = 0.0f; }

  const float scale = 0.03125f;  // 1/sqrt(1024)
  const int sr = tid >> 2, sc16 = (tid & 3) * 16;  // staging 64 rows x 64 cols

  for (int kv0 = 0; kv0 < q0 + 64; kv0 += 64) {
    f16x8 k0v = *(const f16x8*)(Kb + (size_t)(kv0 + sr) * DM + sc16);
    f16x8 k1v = *(const f16x8*)(Kb + (size_t)(kv0 + sr) * DM + sc16 + 8);
    f16x8 v0v = *(const f16x8*)(Vb + (size_t)(kv0 + sr) * DM + sc16);
    f16x8 v1v = *(const f16x8*)(Vb + (size_t)(kv0 + sr) * DM + sc16 + 8);
    __syncthreads();
    *(f16x8*)(&Ks[sr][sc16]) = k0v;
    *(f16x8*)(&Ks[sr][sc16 + 8]) = k1v;
#pragma unroll
    for (int j = 0; j < 8; ++j) {
      Vt[sc16 + j][sr] = v0v[j];
      Vt[sc16 + 8 + j][sr] = v1v[j];
    }
    __syncthreads();
    const bool need_mask = (kv0 + 64 > qt);

    // S = Q K^T : 4 n-tiles
    f32x4 s_t[4];
#pragma unroll
    for (int ni = 0; ni < 4; ++ni) {
      f16x8 kf0 = *(const f16x8*)(&Ks[ni * 16 + fl][fh * 8]);
      f16x8 kf1 = *(const f16x8*)(&Ks[ni * 16 + fl][32 + fh * 8]);
      f32x4 z = {0.f, 0.f, 0.f, 0.f};
      z = __builtin_amdgcn_mfma_f32_16x16x32_f16(qf[0], kf0, z, 0, 0, 0);
      z = __builtin_amdgcn_mfma_f32_16x16x32_f16(qf[1], kf1, z, 0, 0, 0);
      s_t[ni] = z;
    }

    // online softmax; write P straight to per-wave LDS
    float alpha[4];
#pragma unroll
    for (int r = 0; r < 4; ++r) {
      const int row = qt + fh * 4 + r;
      float v[4];
#pragma unroll
      for (int ni = 0; ni < 4; ++ni) {
        v[ni] = s_t[ni][r] * scale;
        if (need_mask && (kv0 + ni * 16 + fl > row)) v[ni] = NEG_BIG;
      }
      float mx = fmaxf(fmaxf(v[0], v[1]), fmaxf(v[2], v[3]));
#pragma unroll
      for (int off = 1; off < 16; off <<= 1)
        mx = fmaxf(mx, __shfl_xor(mx, off, 64));
      const float mn = fmaxf(m_r[r], mx);
      const float a = __expf(m_r[r] - mn);
      float rs = 0.0f;
#pragma unroll
      for (int ni = 0; ni < 4; ++ni) {
        const float pv = __expf(v[ni] - mn);
        rs += pv;
        Pl[wave][fh * 4 + r][ni * 16 + fl] = (_Float16)pv;
      }
#pragma unroll
      for (int off = 1; off < 16; off <<= 1)
        rs += __shfl_xor(rs, off, 64);
      l_r[r] = l_r[r] * a + rs;
      m_r[r] = mn;
      alpha[r] = a;
    }

#pragma unroll
    for (int ni = 0; ni < 4; ++ni)
#pragma unroll
      for (int r = 0; r < 4; ++r) o_acc[ni][r] *= alpha[r];

    // P (same-wave LDS round-trip): wait for our ds_writes, read A-frags
    asm volatile("s_waitcnt lgkmcnt(0)" ::: "memory");
    f16x8 pf[2];
#pragma unroll
    for (int kh = 0; kh < 2; ++kh)
      pf[kh] = *(const f16x8*)(&Pl[wave][fl][kh * 32 + fh * 8]);

#pragma unroll
    for (int ni = 0; ni < 4; ++ni) {
      f16x8 vf0 = *(const f16x8*)(&Vt[ni * 16 + fl][fh * 8]);
      f16x8 vf1 = *(const f16x8*)(&Vt[ni * 16 + fl][32 + fh * 8]);
      o_acc[ni] = __builtin_amdgcn_mfma_f32_16x16x32_f16(pf[0], vf0, o_acc[ni], 0, 0, 0);
      o_acc[ni] = __builtin_amdgcn_mfma_f32_16x16x32_f16(pf[1], vf1, o_acc[ni], 0, 0, 0);
    }
  }

  // epilogue
  float inv_l[4];
#pragma unroll
  for (int r = 0; r < 4; ++r) inv_l[r] = 1.0f / l_r[r];
#pragma unroll
  for (int ni = 0; ni < 4; ++ni)
#pragma unroll
    for (int r = 0; r < 4; ++r) {
      const int qg = qt + fh * 4 + r;
      O[((size_t)b * SEQ + qg) * DM + h * HD + ni * 16 + fl] =
          (_Float16)(o_acc[ni][r] * inv_l[r]);
    }
}

// ---------------------------------------------------------------------------
extern "C" void kernel_launch(void* const* d_in, const int* in_sizes, int n_in,
                              void* d_out, int out_size, void* d_ws, size_t ws_size,
                              hipStream_t stream) {
  const float* x = (const float*)d_in[0];
  const float* qw = (const float*)d_in[1];
  const float* kw = (const float*)d_in[2];
  const float* vw = (const float*)d_in[3];
  const float* ow = (const float*)d_in[4];
  float* out = (float*)d_out;

  const size_t MD = (size_t)MTOT * DM;  // 4M elements
  _Float16* x16 = (_Float16*)d_ws;      // [0, 4M) ; later reused as attention M
  _Float16* wT = x16 + MD;              // [4M, 8M): qwT,kwT,vwT,owT
  _Float16* Qw = wT + 4 * (size_t)DM * DM;  // [8M, 12M)
  _Float16* Kw = Qw + MD;               // [12M, 16M)
  _Float16* Vw = Kw + MD;               // [16M, 20M)
  _Float16* Mw = x16;                   // attention output reuses x16

  convert_x<<<MD / (256 * 8), 256, 0, stream>>>(x, x16);
  transpose_w<<<dim3(16, 16, 4), 256, 0, stream>>>(qw, kw, vw, ow, wT);

  // Fused QKV (N = 3072) with RoPE applied to Q,K in the epilogue
  gemm128<true, false, true><<<dim3(24, MTOT / 128), 256, 0, stream>>>(x16, wT, Qw, MTOT, DM);

  attn_kernel<<<dim3(SEQ / 64, 32), 256, 0, stream>>>(Qw, Kw, Vw, Mw);

  gemm128<false, true, false><<<dim3(8, MTOT / 128), 256, 0, stream>>>(
      Mw, wT + 3 * (size_t)DM * DM, out, MTOT, DM);
}

// Round 7
// 283.206 us; speedup vs baseline: 1.0574x; 1.0574x over previous
//
#include <hip/hip_runtime.h>
#include <math.h>

typedef _Float16 f16x8 __attribute__((ext_vector_type(8)));
typedef float f32x4 __attribute__((ext_vector_type(4)));

#define SEQ 2048
#define DM 1024
#define NH 16
#define HD 64
#define MTOT 4096   // batch*seq

#define NEG_BIG (-30000.0f)

// ---------------------------------------------------------------------------
// fp32 -> fp16 straight convert (x): n multiple of 2048.
// ---------------------------------------------------------------------------
__global__ __launch_bounds__(256) void convert_x(const float* __restrict__ src,
                                                 _Float16* __restrict__ dst) {
  const int i = (blockIdx.x * 256 + threadIdx.x) * 8;
  f32x4 a = *(const f32x4*)(src + i);
  f32x4 b = *(const f32x4*)(src + i + 4);
  f16x8 o;
#pragma unroll
  for (int j = 0; j < 4; ++j) { o[j] = (_Float16)a[j]; o[4 + j] = (_Float16)b[j]; }
  *(f16x8*)(dst + i) = o;
}

// ---------------------------------------------------------------------------
// Weight transpose+convert: w fp32 [k][n] (1024x1024) -> wT fp16 [n][k].
// ---------------------------------------------------------------------------
__global__ __launch_bounds__(256) void transpose_w(const float* __restrict__ q,
                                                   const float* __restrict__ k,
                                                   const float* __restrict__ v,
                                                   const float* __restrict__ o,
                                                   _Float16* __restrict__ dstBase) {
  __shared__ float Ts[64][65];
  const float* srcs[4] = {q, k, v, o};
  const float* src = srcs[blockIdx.z];
  _Float16* dst = dstBase + (size_t)blockIdx.z * DM * DM;
  const int t = threadIdx.x;
  const int k0 = blockIdx.y * 64, n0 = blockIdx.x * 64;
  const int r = t >> 2, c4 = (t & 3) * 16;
  const float* sp = src + (size_t)(k0 + r) * DM + n0 + c4;
#pragma unroll
  for (int j = 0; j < 4; ++j) {
    f32x4 vv = *(const f32x4*)(sp + j * 4);
#pragma unroll
    for (int e = 0; e < 4; ++e) Ts[r][c4 + j * 4 + e] = vv[e];
  }
  __syncthreads();
  f16x8 o0, o1;
#pragma unroll
  for (int j = 0; j < 8; ++j) {
    o0[j] = (_Float16)Ts[c4 + j][r];
    o1[j] = (_Float16)Ts[c4 + 8 + j][r];
  }
  _Float16* dp = dst + (size_t)(n0 + r) * DM + k0 + c4;
  *(f16x8*)(dp) = o0;
  *(f16x8*)(dp + 8) = o1;
}

// ---------------------------------------------------------------------------
// GEMM: Y = A(M,K) @ BT^T, BT fp16 [n][k]. 128x128 tile, 4 waves each 64x64.
// FUSED3: BT = 3 concatenated mats (Q,K,V). ROPE: apply RoPE in epilogue to
// mats 0,1 — pair (2d2,2d2+1) = lanes (fl, fl^1): one shfl_xor + sincos.
// ---------------------------------------------------------------------------
template <bool FUSED3, bool OUTF32, bool ROPE>
__global__ __launch_bounds__(256) void gemm128(const _Float16* __restrict__ A,
                                               const _Float16* __restrict__ BT,
                                               void* __restrict__ Yv,
                                               int M, int K) {
  __shared__ _Float16 As[128][40];
  __shared__ _Float16 Bs[128][40];
  const int tid = threadIdx.x;
  const int lane = tid & 63;
  const int fl = lane & 15, fh = lane >> 4;
  const int wave = tid >> 6;
  const int m0 = blockIdx.y * 128;
  int n0 = blockIdx.x * 128;
  int mat = 0;
  const _Float16* Bp = BT;
  char* Yp = (char*)Yv;
  if (FUSED3) {
    mat = n0 >> 10;
    n0 &= 1023;
    Bp = BT + (size_t)mat * DM * DM;
    Yp += (size_t)mat * M * DM * (OUTF32 ? 4 : 2);
  }
  const int wm = (wave >> 1) * 64, wn = (wave & 1) * 64;
  const int sr = tid >> 2, sc = (tid & 3) * 8;

  f32x4 acc[4][4] = {};

  for (int k0 = 0; k0 < K; k0 += 32) {
    f16x8 a0 = *(const f16x8*)(A + (size_t)(m0 + sr) * K + k0 + sc);
    f16x8 a1 = *(const f16x8*)(A + (size_t)(m0 + 64 + sr) * K + k0 + sc);
    f16x8 b0 = *(const f16x8*)(Bp + (size_t)(n0 + sr) * K + k0 + sc);
    f16x8 b1 = *(const f16x8*)(Bp + (size_t)(n0 + 64 + sr) * K + k0 + sc);
    __syncthreads();
    *(f16x8*)(&As[sr][sc]) = a0;
    *(f16x8*)(&As[64 + sr][sc]) = a1;
    *(f16x8*)(&Bs[sr][sc]) = b0;
    *(f16x8*)(&Bs[64 + sr][sc]) = b1;
    __syncthreads();
    f16x8 af[4], bf[4];
#pragma unroll
    for (int mi = 0; mi < 4; ++mi)
      af[mi] = *(const f16x8*)(&As[wm + mi * 16 + fl][fh * 8]);
#pragma unroll
    for (int ni = 0; ni < 4; ++ni)
      bf[ni] = *(const f16x8*)(&Bs[wn + ni * 16 + fl][fh * 8]);
#pragma unroll
    for (int mi = 0; mi < 4; ++mi)
#pragma unroll
      for (int ni = 0; ni < 4; ++ni)
        acc[mi][ni] = __builtin_amdgcn_mfma_f32_16x16x32_f16(af[mi], bf[ni], acc[mi][ni], 0, 0, 0);
  }

  // C/D: row = fh*4 + r, col = fl
#pragma unroll
  for (int mi = 0; mi < 4; ++mi)
#pragma unroll
    for (int ni = 0; ni < 4; ++ni) {
      const int gm = m0 + wm + mi * 16 + fh * 4;
      const int gn = n0 + wn + ni * 16 + fl;
      if (ROPE && mat < 2) {
        const int d2 = (gn & 63) >> 1;
        const float inv = __powf(10000.0f, -(float)d2 * (1.0f / 32.0f));
        const float sgn = (gn & 1) ? 1.0f : -1.0f;
#pragma unroll
        for (int r = 0; r < 4; ++r) {
          const int s = (gm + r) & (SEQ - 1);
          float c, sn;
          __sincosf((float)s * inv, &sn, &c);
          const float v = acc[mi][ni][r];
          const float p = __shfl_xor(v, 1, 64);
          acc[mi][ni][r] = v * c + sgn * p * sn;
        }
      }
#pragma unroll
      for (int r = 0; r < 4; ++r) {
        if (OUTF32)
          ((float*)Yp)[(size_t)(gm + r) * DM + gn] = acc[mi][ni][r];
        else
          ((_Float16*)Yp)[(size_t)(gm + r) * DM + gn] = (_Float16)acc[mi][ni][r];
      }
    }
}

// ---------------------------------------------------------------------------
// Flash attention, causal. Block = 512 thr = 8 waves; block covers 128 q rows
// (16 per wave); KV chunks of 64 staged block-wide (K rows, V transposed).
// V-transpose writes staggered by lane (jj = (t+e)&7): bank = 4*jj + sr>>1
// covers all 32 banks, paired lanes merge -> conflict-free (vs 8-way before).
// LDS 36.9 KB; grid 512 = 2 blocks/CU -> 16 waves/CU; 52 VGPR.
// ---------------------------------------------------------------------------
__global__ __launch_bounds__(512) void attn_kernel(const _Float16* __restrict__ Q,
                                                   const _Float16* __restrict__ K,
                                                   const _Float16* __restrict__ V,
                                                   _Float16* __restrict__ O) {
  __shared__ _Float16 Ks[64][72];      // [kv][d]
  __shared__ _Float16 Vt[64][72];      // [d][kv]
  __shared__ _Float16 Pl[8][16][72];   // per-wave P [q][kv]

  const int tid = threadIdx.x;
  const int lane = tid & 63;
  const int fl = lane & 15, fh = lane >> 4;
  const int wave = tid >> 6;
  const int bh = blockIdx.y;
  const int b = bh >> 4, h = bh & 15;
  const int q0 = blockIdx.x * 128;
  const int qt = q0 + wave * 16;

  const _Float16* Qb = Q + (size_t)b * SEQ * DM + h * HD;
  const _Float16* Kb = K + (size_t)b * SEQ * DM + h * HD;
  const _Float16* Vb = V + (size_t)b * SEQ * DM + h * HD;

  f16x8 qf[2];
#pragma unroll
  for (int kh = 0; kh < 2; ++kh)
    qf[kh] = *(const f16x8*)(Qb + (size_t)(qt + fl) * DM + kh * 32 + fh * 8);

  f32x4 o_acc[4] = {};
  float m_r[4], l_r[4];
#pragma unroll
  for (int r = 0; r < 4; ++r) { m_r[r] = NEG_BIG; l_r[r] = 0.0f; }

  const float scale = 0.03125f;  // 1/sqrt(1024)
  const int sr = tid >> 3, e = tid & 7;  // staging: 64 rows x 8 col-groups
  const int sc8 = e * 8;

  for (int kv0 = 0; kv0 < q0 + 128; kv0 += 64) {
    f16x8 kv = *(const f16x8*)(Kb + (size_t)(kv0 + sr) * DM + sc8);
    f16x8 vv = *(const f16x8*)(Vb + (size_t)(kv0 + sr) * DM + sc8);
    __syncthreads();
    *(f16x8*)(&Ks[sr][sc8]) = kv;
#pragma unroll
    for (int t = 0; t < 8; ++t) {
      const int jj = (t + e) & 7;     // staggered: conflict-free banks
      Vt[sc8 + jj][sr] = vv[jj];
    }
    __syncthreads();
    if (kv0 >= qt + 16) continue;  // fully masked for this wave
    const bool need_mask = (kv0 + 64 > qt);

    // S = Q K^T : 4 n-tiles
    f32x4 s_t[4];
#pragma unroll
    for (int ni = 0; ni < 4; ++ni) {
      f16x8 kf0 = *(const f16x8*)(&Ks[ni * 16 + fl][fh * 8]);
      f16x8 kf1 = *(const f16x8*)(&Ks[ni * 16 + fl][32 + fh * 8]);
      f32x4 z = {0.f, 0.f, 0.f, 0.f};
      z = __builtin_amdgcn_mfma_f32_16x16x32_f16(qf[0], kf0, z, 0, 0, 0);
      z = __builtin_amdgcn_mfma_f32_16x16x32_f16(qf[1], kf1, z, 0, 0, 0);
      s_t[ni] = z;
    }

    // online softmax; write P straight to per-wave LDS
    float alpha[4];
#pragma unroll
    for (int r = 0; r < 4; ++r) {
      const int row = qt + fh * 4 + r;
      float v[4];
#pragma unroll
      for (int ni = 0; ni < 4; ++ni) {
        v[ni] = s_t[ni][r] * scale;
        if (need_mask && (kv0 + ni * 16 + fl > row)) v[ni] = NEG_BIG;
      }
      float mx = fmaxf(fmaxf(v[0], v[1]), fmaxf(v[2], v[3]));
#pragma unroll
      for (int off = 1; off < 16; off <<= 1)
        mx = fmaxf(mx, __shfl_xor(mx, off, 64));
      const float mn = fmaxf(m_r[r], mx);
      const float a = __expf(m_r[r] - mn);
      float rs = 0.0f;
#pragma unroll
      for (int ni = 0; ni < 4; ++ni) {
        const float pv = __expf(v[ni] - mn);
        rs += pv;
        Pl[wave][fh * 4 + r][ni * 16 + fl] = (_Float16)pv;
      }
#pragma unroll
      for (int off = 1; off < 16; off <<= 1)
        rs += __shfl_xor(rs, off, 64);
      l_r[r] = l_r[r] * a + rs;
      m_r[r] = mn;
      alpha[r] = a;
    }

#pragma unroll
    for (int ni = 0; ni < 4; ++ni)
#pragma unroll
      for (int r = 0; r < 4; ++r) o_acc[ni][r] *= alpha[r];

    // P (same-wave LDS round-trip): wait for our ds_writes, read A-frags
    asm volatile("s_waitcnt lgkmcnt(0)" ::: "memory");
    f16x8 pf[2];
#pragma unroll
    for (int kh = 0; kh < 2; ++kh)
      pf[kh] = *(const f16x8*)(&Pl[wave][fl][kh * 32 + fh * 8]);

#pragma unroll
    for (int ni = 0; ni < 4; ++ni) {
      f16x8 vf0 = *(const f16x8*)(&Vt[ni * 16 + fl][fh * 8]);
      f16x8 vf1 = *(const f16x8*)(&Vt[ni * 16 + fl][32 + fh * 8]);
      o_acc[ni] = __builtin_amdgcn_mfma_f32_16x16x32_f16(pf[0], vf0, o_acc[ni], 0, 0, 0);
      o_acc[ni] = __builtin_amdgcn_mfma_f32_16x16x32_f16(pf[1], vf1, o_acc[ni], 0, 0, 0);
    }
  }

  // epilogue
  float inv_l[4];
#pragma unroll
  for (int r = 0; r < 4; ++r) inv_l[r] = 1.0f / l_r[r];
#pragma unroll
  for (int ni = 0; ni < 4; ++ni)
#pragma unroll
    for (int r = 0; r < 4; ++r) {
      const int qg = qt + fh * 4 + r;
      O[((size_t)b * SEQ + qg) * DM + h * HD + ni * 16 + fl] =
          (_Float16)(o_acc[ni][r] * inv_l[r]);
    }
}

// ---------------------------------------------------------------------------
extern "C" void kernel_launch(void* const* d_in, const int* in_sizes, int n_in,
                              void* d_out, int out_size, void* d_ws, size_t ws_size,
                              hipStream_t stream) {
  const float* x = (const float*)d_in[0];
  const float* qw = (const float*)d_in[1];
  const float* kw = (const float*)d_in[2];
  const float* vw = (const float*)d_in[3];
  const float* ow = (const float*)d_in[4];
  float* out = (float*)d_out;

  const size_t MD = (size_t)MTOT * DM;  // 4M elements
  _Float16* x16 = (_Float16*)d_ws;      // [0, 4M) ; later reused as attention M
  _Float16* wT = x16 + MD;              // [4M, 8M): qwT,kwT,vwT,owT
  _Float16* Qw = wT + 4 * (size_t)DM * DM;  // [8M, 12M)
  _Float16* Kw = Qw + MD;               // [12M, 16M)
  _Float16* Vw = Kw + MD;               // [16M, 20M)
  _Float16* Mw = x16;                   // attention output reuses x16

  convert_x<<<MD / (256 * 8), 256, 0, stream>>>(x, x16);
  transpose_w<<<dim3(16, 16, 4), 256, 0, stream>>>(qw, kw, vw, ow, wT);

  // Fused QKV (N = 3072) with RoPE applied to Q,K in the epilogue
  gemm128<true, false, true><<<dim3(24, MTOT / 128), 256, 0, stream>>>(x16, wT, Qw, MTOT, DM);

  attn_kernel<<<dim3(SEQ / 128, 32), 512, 0, stream>>>(Qw, Kw, Vw, Mw);

  gemm128<false, true, false><<<dim3(8, MTOT / 128), 256, 0, stream>>>(
      Mw, wT + 3 * (size_t)DM * DM, out, MTOT, DM);
}

// Round 8
// 275.189 us; speedup vs baseline: 1.0882x; 1.0291x over previous
//
#include <hip/hip_runtime.h>
#include <math.h>

typedef _Float16 f16x8 __attribute__((ext_vector_type(8)));
typedef float f32x4 __attribute__((ext_vector_type(4)));

#define SEQ 2048
#define DM 1024
#define NH 16
#define HD 64
#define MTOT 4096   // batch*seq

#define NEG_BIG (-30000.0f)

__device__ __forceinline__ void gl_lds16(const _Float16* g, _Float16* l) {
  __builtin_amdgcn_global_load_lds(
      (const __attribute__((address_space(1))) unsigned int*)g,
      (__attribute__((address_space(3))) unsigned int*)l, 16, 0, 0);
}

// ---------------------------------------------------------------------------
// fp32 -> fp16 straight convert (x).
// ---------------------------------------------------------------------------
__global__ __launch_bounds__(256) void convert_x(const float* __restrict__ src,
                                                 _Float16* __restrict__ dst) {
  const int i = (blockIdx.x * 256 + threadIdx.x) * 8;
  f32x4 a = *(const f32x4*)(src + i);
  f32x4 b = *(const f32x4*)(src + i + 4);
  f16x8 o;
#pragma unroll
  for (int j = 0; j < 4; ++j) { o[j] = (_Float16)a[j]; o[4 + j] = (_Float16)b[j]; }
  *(f16x8*)(dst + i) = o;
}

// ---------------------------------------------------------------------------
// Weight transpose+convert: w fp32 [k][n] (1024x1024) -> wT fp16 [n][k].
// ---------------------------------------------------------------------------
__global__ __launch_bounds__(256) void transpose_w(const float* __restrict__ q,
                                                   const float* __restrict__ k,
                                                   const float* __restrict__ v,
                                                   const float* __restrict__ o,
                                                   _Float16* __restrict__ dstBase) {
  __shared__ float Ts[64][65];
  const float* srcs[4] = {q, k, v, o};
  const float* src = srcs[blockIdx.z];
  _Float16* dst = dstBase + (size_t)blockIdx.z * DM * DM;
  const int t = threadIdx.x;
  const int k0 = blockIdx.y * 64, n0 = blockIdx.x * 64;
  const int r = t >> 2, c4 = (t & 3) * 16;
  const float* sp = src + (size_t)(k0 + r) * DM + n0 + c4;
#pragma unroll
  for (int j = 0; j < 4; ++j) {
    f32x4 vv = *(const f32x4*)(sp + j * 4);
#pragma unroll
    for (int e = 0; e < 4; ++e) Ts[r][c4 + j * 4 + e] = vv[e];
  }
  __syncthreads();
  f16x8 o0, o1;
#pragma unroll
  for (int j = 0; j < 8; ++j) {
    o0[j] = (_Float16)Ts[c4 + j][r];
    o1[j] = (_Float16)Ts[c4 + 8 + j][r];
  }
  _Float16* dp = dst + (size_t)(n0 + r) * DM + k0 + c4;
  *(f16x8*)(dp) = o0;
  *(f16x8*)(dp + 8) = o1;
}

// ---------------------------------------------------------------------------
// GEMM (m97 structure): Y = A(M,K) @ BT^T, BT fp16 [n][k]. 128x128 tile,
// 4 waves each 64x64 (4x4 16x16x32 MFMAs), BK=32, UNPADDED LDS, staging via
// global_load_lds (wave-uniform base + lane*16, lane-contiguous rows).
// FUSED3: BT = 3 concatenated mats (Q,K,V). ROPE: epilogue RoPE on mats 0,1.
// ---------------------------------------------------------------------------
template <bool FUSED3, bool OUTF32, bool ROPE>
__global__ __launch_bounds__(256) void gemm128(const _Float16* __restrict__ A,
                                               const _Float16* __restrict__ BT,
                                               void* __restrict__ Yv,
                                               int M, int K) {
  __shared__ _Float16 As[128 * 32];
  __shared__ _Float16 Bs[128 * 32];
  const int tid = threadIdx.x;
  const int lane = tid & 63;
  const int fl = lane & 15, fh = lane >> 4;
  const int wave = tid >> 6;
  const int m0 = blockIdx.y * 128;
  int n0 = blockIdx.x * 128;
  int mat = 0;
  const _Float16* Bp = BT;
  char* Yp = (char*)Yv;
  if (FUSED3) {
    mat = n0 >> 10;
    n0 &= 1023;
    Bp = BT + (size_t)mat * DM * DM;
    Yp += (size_t)mat * M * DM * (OUTF32 ? 4 : 2);
  }
  const int wm = (wave >> 1) * 64, wn = (wave & 1) * 64;

  // staging: wave w covers A rows [w*32, w*32+32) and B rows [w*32, w*32+32)
  const int l4 = lane >> 2, lc = (lane & 3) * 8;
  const _Float16* ga0 = A + (size_t)(m0 + wave * 32 + l4) * K + lc;
  const _Float16* ga1 = ga0 + (size_t)16 * K;
  const _Float16* gb0 = Bp + (size_t)(n0 + wave * 32 + l4) * K + lc;
  const _Float16* gb1 = gb0 + (size_t)16 * K;
  _Float16* la0 = &As[(wave * 32) * 32];
  _Float16* la1 = &As[(wave * 32 + 16) * 32];
  _Float16* lb0 = &Bs[(wave * 32) * 32];
  _Float16* lb1 = &Bs[(wave * 32 + 16) * 32];

  f32x4 acc[4][4] = {};

  for (int k0 = 0; k0 < K; k0 += 32) {
    __syncthreads();
    gl_lds16(ga0 + k0, la0);
    gl_lds16(ga1 + k0, la1);
    gl_lds16(gb0 + k0, lb0);
    gl_lds16(gb1 + k0, lb1);
    __syncthreads();
    f16x8 af[4], bf[4];
#pragma unroll
    for (int mi = 0; mi < 4; ++mi)
      af[mi] = *(const f16x8*)(&As[(wm + mi * 16 + fl) * 32 + fh * 8]);
#pragma unroll
    for (int ni = 0; ni < 4; ++ni)
      bf[ni] = *(const f16x8*)(&Bs[(wn + ni * 16 + fl) * 32 + fh * 8]);
#pragma unroll
    for (int mi = 0; mi < 4; ++mi)
#pragma unroll
      for (int ni = 0; ni < 4; ++ni)
        acc[mi][ni] = __builtin_amdgcn_mfma_f32_16x16x32_f16(af[mi], bf[ni], acc[mi][ni], 0, 0, 0);
  }

  // C/D: row = fh*4 + r, col = fl
#pragma unroll
  for (int mi = 0; mi < 4; ++mi)
#pragma unroll
    for (int ni = 0; ni < 4; ++ni) {
      const int gm = m0 + wm + mi * 16 + fh * 4;
      const int gn = n0 + wn + ni * 16 + fl;
      if (ROPE && mat < 2) {
        const int d2 = (gn & 63) >> 1;
        const float inv = __powf(10000.0f, -(float)d2 * (1.0f / 32.0f));
        const float sgn = (gn & 1) ? 1.0f : -1.0f;
#pragma unroll
        for (int r = 0; r < 4; ++r) {
          const int s = (gm + r) & (SEQ - 1);
          float c, sn;
          __sincosf((float)s * inv, &sn, &c);
          const float v = acc[mi][ni][r];
          const float p = __shfl_xor(v, 1, 64);
          acc[mi][ni][r] = v * c + sgn * p * sn;
        }
      }
#pragma unroll
      for (int r = 0; r < 4; ++r) {
        if (OUTF32)
          ((float*)Yp)[(size_t)(gm + r) * DM + gn] = acc[mi][ni][r];
        else
          ((_Float16*)Yp)[(size_t)(gm + r) * DM + gn] = (_Float16)acc[mi][ni][r];
      }
    }
}

// ---------------------------------------------------------------------------
// Flash attention, causal. Block = 512 thr = 8 waves; 128 q rows (16/wave);
// KV chunk = 128 per staging round (barriers halved vs 64-chunk). Softmax in
// one pass over 8 n-tiles; P->A-layout round-trip in two 64-kv halves via a
// single 64-wide per-wave Pl (same-wave DS ops are in-order; lgkmcnt waits).
// LDS 54.3 KB -> 2 blocks/CU, 16 waves/CU.
// ---------------------------------------------------------------------------
__global__ __launch_bounds__(512) void attn_kernel(const _Float16* __restrict__ Q,
                                                   const _Float16* __restrict__ K,
                                                   const _Float16* __restrict__ V,
                                                   _Float16* __restrict__ O) {
  __shared__ _Float16 Ks[128][72];     // [kv][d]
  __shared__ _Float16 Vt[64][136];     // [d][kv]
  __shared__ _Float16 Pl[8][16][72];   // per-wave P half [q][kv64]

  const int tid = threadIdx.x;
  const int lane = tid & 63;
  const int fl = lane & 15, fh = lane >> 4;
  const int wave = tid >> 6;
  const int bh = blockIdx.y;
  const int b = bh >> 4, h = bh & 15;
  const int q0 = blockIdx.x * 128;
  const int qt = q0 + wave * 16;

  const _Float16* Qb = Q + (size_t)b * SEQ * DM + h * HD;
  const _Float16* Kb = K + (size_t)b * SEQ * DM + h * HD;
  const _Float16* Vb = V + (size_t)b * SEQ * DM + h * HD;

  f16x8 qf[2];
#pragma unroll
  for (int kh = 0; kh < 2; ++kh)
    qf[kh] = *(const f16x8*)(Qb + (size_t)(qt + fl) * DM + kh * 32 + fh * 8);

  f32x4 o_acc[4] = {};
  float m_r[4], l_r[4];
#pragma unroll
  for (int r = 0; r < 4; ++r) { m_r[r] = NEG_BIG; l_r[r] = 0.0f; }

  const float scale = 0.03125f;  // 1/sqrt(1024)
  const int sr = tid >> 3, e = tid & 7;  // staging: 64 rows x 8 col-groups, x2
  const int sc8 = e * 8;

  for (int kv0 = 0; kv0 < q0 + 128; kv0 += 128) {
    f16x8 k0v = *(const f16x8*)(Kb + (size_t)(kv0 + sr) * DM + sc8);
    f16x8 k1v = *(const f16x8*)(Kb + (size_t)(kv0 + 64 + sr) * DM + sc8);
    f16x8 v0v = *(const f16x8*)(Vb + (size_t)(kv0 + sr) * DM + sc8);
    f16x8 v1v = *(const f16x8*)(Vb + (size_t)(kv0 + 64 + sr) * DM + sc8);
    __syncthreads();
    *(f16x8*)(&Ks[sr][sc8]) = k0v;
    *(f16x8*)(&Ks[64 + sr][sc8]) = k1v;
#pragma unroll
    for (int t = 0; t < 8; ++t) {
      const int jj = (t + e) & 7;     // staggered: conflict-free banks
      Vt[sc8 + jj][sr] = v0v[jj];
      Vt[sc8 + jj][64 + sr] = v1v[jj];
    }
    __syncthreads();
    const bool need_mask = (kv0 + 127 > qt);

    // S = Q K^T : 8 n-tiles
    f32x4 s_t[8];
#pragma unroll
    for (int ni = 0; ni < 8; ++ni) {
      f16x8 kf0 = *(const f16x8*)(&Ks[ni * 16 + fl][fh * 8]);
      f16x8 kf1 = *(const f16x8*)(&Ks[ni * 16 + fl][32 + fh * 8]);
      f32x4 z = {0.f, 0.f, 0.f, 0.f};
      z = __builtin_amdgcn_mfma_f32_16x16x32_f16(qf[0], kf0, z, 0, 0, 0);
      z = __builtin_amdgcn_mfma_f32_16x16x32_f16(qf[1], kf1, z, 0, 0, 0);
      s_t[ni] = z;
    }

    // online softmax over all 128 cols; pv kept in s_t regs
    float alpha[4];
#pragma unroll
    for (int r = 0; r < 4; ++r) {
      const int row = qt + fh * 4 + r;
      float v[8];
#pragma unroll
      for (int ni = 0; ni < 8; ++ni) {
        v[ni] = s_t[ni][r] * scale;
        if (need_mask && (kv0 + ni * 16 + fl > row)) v[ni] = NEG_BIG;
      }
      float mx = v[0];
#pragma unroll
      for (int ni = 1; ni < 8; ++ni) mx = fmaxf(mx, v[ni]);
#pragma unroll
      for (int off = 1; off < 16; off <<= 1)
        mx = fmaxf(mx, __shfl_xor(mx, off, 64));
      const float mn = fmaxf(m_r[r], mx);
      const float a = __expf(m_r[r] - mn);
      float rs = 0.0f;
#pragma unroll
      for (int ni = 0; ni < 8; ++ni) {
        const float pv = __expf(v[ni] - mn);
        rs += pv;
        s_t[ni][r] = pv;
      }
      // write first-half P now
#pragma unroll
      for (int ni = 0; ni < 4; ++ni)
        Pl[wave][fh * 4 + r][ni * 16 + fl] = (_Float16)s_t[ni][r];
#pragma unroll
      for (int off = 1; off < 16; off <<= 1)
        rs += __shfl_xor(rs, off, 64);
      l_r[r] = l_r[r] * a + rs;
      m_r[r] = mn;
      alpha[r] = a;
    }

#pragma unroll
    for (int ni = 0; ni < 4; ++ni)
#pragma unroll
      for (int r = 0; r < 4; ++r) o_acc[ni][r] *= alpha[r];

    // PV half 1 (kv 0..63)
    asm volatile("s_waitcnt lgkmcnt(0)" ::: "memory");
    {
      f16x8 pf0 = *(const f16x8*)(&Pl[wave][fl][fh * 8]);
      f16x8 pf1 = *(const f16x8*)(&Pl[wave][fl][32 + fh * 8]);
#pragma unroll
      for (int ni = 0; ni < 4; ++ni) {
        f16x8 vf0 = *(const f16x8*)(&Vt[ni * 16 + fl][fh * 8]);
        f16x8 vf1 = *(const f16x8*)(&Vt[ni * 16 + fl][32 + fh * 8]);
        o_acc[ni] = __builtin_amdgcn_mfma_f32_16x16x32_f16(pf0, vf0, o_acc[ni], 0, 0, 0);
        o_acc[ni] = __builtin_amdgcn_mfma_f32_16x16x32_f16(pf1, vf1, o_acc[ni], 0, 0, 0);
      }
    }
    // write second-half P (after pf reads: same-wave DS ops are in-order)
#pragma unroll
    for (int r = 0; r < 4; ++r)
#pragma unroll
      for (int ni = 4; ni < 8; ++ni)
        Pl[wave][fh * 4 + r][(ni - 4) * 16 + fl] = (_Float16)s_t[ni][r];
    asm volatile("s_waitcnt lgkmcnt(0)" ::: "memory");
    {
      f16x8 pf0 = *(const f16x8*)(&Pl[wave][fl][fh * 8]);
      f16x8 pf1 = *(const f16x8*)(&Pl[wave][fl][32 + fh * 8]);
#pragma unroll
      for (int ni = 0; ni < 4; ++ni) {
        f16x8 vf0 = *(const f16x8*)(&Vt[ni * 16 + fl][64 + fh * 8]);
        f16x8 vf1 = *(const f16x8*)(&Vt[ni * 16 + fl][96 + fh * 8]);
        o_acc[ni] = __builtin_amdgcn_mfma_f32_16x16x32_f16(pf0, vf0, o_acc[ni], 0, 0, 0);
        o_acc[ni] = __builtin_amdgcn_mfma_f32_16x16x32_f16(pf1, vf1, o_acc[ni], 0, 0, 0);
      }
    }
  }

  // epilogue
  float inv_l[4];
#pragma unroll
  for (int r = 0; r < 4; ++r) inv_l[r] = 1.0f / l_r[r];
#pragma unroll
  for (int ni = 0; ni < 4; ++ni)
#pragma unroll
    for (int r = 0; r < 4; ++r) {
      const int qg = qt + fh * 4 + r;
      O[((size_t)b * SEQ + qg) * DM + h * HD + ni * 16 + fl] =
          (_Float16)(o_acc[ni][r] * inv_l[r]);
    }
}

// ---------------------------------------------------------------------------
extern "C" void kernel_launch(void* const* d_in, const int* in_sizes, int n_in,
                              void* d_out, int out_size, void* d_ws, size_t ws_size,
                              hipStream_t stream) {
  const float* x = (const float*)d_in[0];
  const float* qw = (const float*)d_in[1];
  const float* kw = (const float*)d_in[2];
  const float* vw = (const float*)d_in[3];
  const float* ow = (const float*)d_in[4];
  float* out = (float*)d_out;

  const size_t MD = (size_t)MTOT * DM;  // 4M elements
  _Float16* x16 = (_Float16*)d_ws;      // [0, 4M) ; later reused as attention M
  _Float16* wT = x16 + MD;              // [4M, 8M): qwT,kwT,vwT,owT
  _Float16* Qw = wT + 4 * (size_t)DM * DM;  // [8M, 12M)
  _Float16* Kw = Qw + MD;               // [12M, 16M)
  _Float16* Vw = Kw + MD;               // [16M, 20M)
  _Float16* Mw = x16;                   // attention output reuses x16

  convert_x<<<MD / (256 * 8), 256, 0, stream>>>(x, x16);
  transpose_w<<<dim3(16, 16, 4), 256, 0, stream>>>(qw, kw, vw, ow, wT);

  // Fused QKV (N = 3072) with RoPE applied to Q,K in the epilogue
  gemm128<true, false, true><<<dim3(24, MTOT / 128), 256, 0, stream>>>(x16, wT, Qw, MTOT, DM);

  attn_kernel<<<dim3(SEQ / 128, 32), 512, 0, stream>>>(Qw, Kw, Vw, Mw);

  gemm128<false, true, false><<<dim3(8, MTOT / 128), 256, 0, stream>>>(
      Mw, wT + 3 * (size_t)DM * DM, out, MTOT, DM);
}

// Round 10
// 217.034 us; speedup vs baseline: 1.3798x; 1.2680x over previous
//
#include <hip/hip_runtime.h>
#include <math.h>

typedef _Float16 f16x8 __attribute__((ext_vector_type(8)));
typedef _Float16 f16x4 __attribute__((ext_vector_type(4)));
typedef float f32x4 __attribute__((ext_vector_type(4)));

#define SEQ 2048
#define DM 1024
#define NH 16
#define HD 64
#define MTOT 4096   // batch*seq

#define NEG_BIG (-30000.0f)

__device__ __forceinline__ void gl_lds16(const _Float16* g, _Float16* l) {
  __builtin_amdgcn_global_load_lds(
      (const __attribute__((address_space(1))) unsigned int*)g,
      (__attribute__((address_space(3))) unsigned int*)l, 16, 0, 0);
}

// ---------------------------------------------------------------------------
// fp32 -> fp16 straight convert (x).
// ---------------------------------------------------------------------------
__global__ __launch_bounds__(256) void convert_x(const float* __restrict__ src,
                                                 _Float16* __restrict__ dst) {
  const int i = (blockIdx.x * 256 + threadIdx.x) * 8;
  f32x4 a = *(const f32x4*)(src + i);
  f32x4 b = *(const f32x4*)(src + i + 4);
  f16x8 o;
#pragma unroll
  for (int j = 0; j < 4; ++j) { o[j] = (_Float16)a[j]; o[4 + j] = (_Float16)b[j]; }
  *(f16x8*)(dst + i) = o;
}

// ---------------------------------------------------------------------------
// Weight transpose+convert: w fp32 [k][n] (1024x1024) -> wT fp16 [n][k].
// ---------------------------------------------------------------------------
__global__ __launch_bounds__(256) void transpose_w(const float* __restrict__ q,
                                                   const float* __restrict__ k,
                                                   const float* __restrict__ v,
                                                   const float* __restrict__ o,
                                                   _Float16* __restrict__ dstBase) {
  __shared__ float Ts[64][65];
  const float* srcs[4] = {q, k, v, o};
  const float* src = srcs[blockIdx.z];
  _Float16* dst = dstBase + (size_t)blockIdx.z * DM * DM;
  const int t = threadIdx.x;
  const int k0 = blockIdx.y * 64, n0 = blockIdx.x * 64;
  const int r = t >> 2, c4 = (t & 3) * 16;
  const float* sp = src + (size_t)(k0 + r) * DM + n0 + c4;
#pragma unroll
  for (int j = 0; j < 4; ++j) {
    f32x4 vv = *(const f32x4*)(sp + j * 4);
#pragma unroll
    for (int e = 0; e < 4; ++e) Ts[r][c4 + j * 4 + e] = vv[e];
  }
  __syncthreads();
  f16x8 o0, o1;
#pragma unroll
  for (int j = 0; j < 8; ++j) {
    o0[j] = (_Float16)Ts[c4 + j][r];
    o1[j] = (_Float16)Ts[c4 + 8 + j][r];
  }
  _Float16* dp = dst + (size_t)(n0 + r) * DM + k0 + c4;
  *(f16x8*)(dp) = o0;
  *(f16x8*)(dp + 8) = o1;
}

// ---------------------------------------------------------------------------
// GEMM (m97 structure): Y = A(M,K) @ BT^T, BT fp16 [n][k]. 128x128 tile,
// 4 waves each 64x64 (4x4 16x16x32 MFMAs), BK=32, UNPADDED LDS, staging via
// global_load_lds. FUSED3: BT = 3 concatenated mats. ROPE: epilogue on mats 0,1.
// ---------------------------------------------------------------------------
template <bool FUSED3, bool OUTF32, bool ROPE>
__global__ __launch_bounds__(256) void gemm128(const _Float16* __restrict__ A,
                                               const _Float16* __restrict__ BT,
                                               void* __restrict__ Yv,
                                               int M, int K) {
  __shared__ _Float16 As[128 * 32];
  __shared__ _Float16 Bs[128 * 32];
  const int tid = threadIdx.x;
  const int lane = tid & 63;
  const int fl = lane & 15, fh = lane >> 4;
  const int wave = tid >> 6;
  const int m0 = blockIdx.y * 128;
  int n0 = blockIdx.x * 128;
  int mat = 0;
  const _Float16* Bp = BT;
  char* Yp = (char*)Yv;
  if (FUSED3) {
    mat = n0 >> 10;
    n0 &= 1023;
    Bp = BT + (size_t)mat * DM * DM;
    Yp += (size_t)mat * M * DM * (OUTF32 ? 4 : 2);
  }
  const int wm = (wave >> 1) * 64, wn = (wave & 1) * 64;

  const int l4 = lane >> 2, lc = (lane & 3) * 8;
  const _Float16* ga0 = A + (size_t)(m0 + wave * 32 + l4) * K + lc;
  const _Float16* ga1 = ga0 + (size_t)16 * K;
  const _Float16* gb0 = Bp + (size_t)(n0 + wave * 32 + l4) * K + lc;
  const _Float16* gb1 = gb0 + (size_t)16 * K;
  _Float16* la0 = &As[(wave * 32) * 32];
  _Float16* la1 = &As[(wave * 32 + 16) * 32];
  _Float16* lb0 = &Bs[(wave * 32) * 32];
  _Float16* lb1 = &Bs[(wave * 32 + 16) * 32];

  f32x4 acc[4][4] = {};

  for (int k0 = 0; k0 < K; k0 += 32) {
    __syncthreads();
    gl_lds16(ga0 + k0, la0);
    gl_lds16(ga1 + k0, la1);
    gl_lds16(gb0 + k0, lb0);
    gl_lds16(gb1 + k0, lb1);
    __syncthreads();
    f16x8 af[4], bf[4];
#pragma unroll
    for (int mi = 0; mi < 4; ++mi)
      af[mi] = *(const f16x8*)(&As[(wm + mi * 16 + fl) * 32 + fh * 8]);
#pragma unroll
    for (int ni = 0; ni < 4; ++ni)
      bf[ni] = *(const f16x8*)(&Bs[(wn + ni * 16 + fl) * 32 + fh * 8]);
#pragma unroll
    for (int mi = 0; mi < 4; ++mi)
#pragma unroll
      for (int ni = 0; ni < 4; ++ni)
        acc[mi][ni] = __builtin_amdgcn_mfma_f32_16x16x32_f16(af[mi], bf[ni], acc[mi][ni], 0, 0, 0);
  }

  // C/D: row = fh*4 + r, col = fl
#pragma unroll
  for (int mi = 0; mi < 4; ++mi)
#pragma unroll
    for (int ni = 0; ni < 4; ++ni) {
      const int gm = m0 + wm + mi * 16 + fh * 4;
      const int gn = n0 + wn + ni * 16 + fl;
      if (ROPE && mat < 2) {
        const int d2 = (gn & 63) >> 1;
        const float inv = __powf(10000.0f, -(float)d2 * (1.0f / 32.0f));
        const float sgn = (gn & 1) ? 1.0f : -1.0f;
#pragma unroll
        for (int r = 0; r < 4; ++r) {
          const int s = (gm + r) & (SEQ - 1);
          float c, sn;
          __sincosf((float)s * inv, &sn, &c);
          const float v = acc[mi][ni][r];
          const float p = __shfl_xor(v, 1, 64);
          acc[mi][ni][r] = v * c + sgn * p * sn;
        }
      }
#pragma unroll
      for (int r = 0; r < 4; ++r) {
        if (OUTF32)
          ((float*)Yp)[(size_t)(gm + r) * DM + gn] = acc[mi][ni][r];
        else
          ((_Float16*)Yp)[(size_t)(gm + r) * DM + gn] = (_Float16)acc[mi][ni][r];
      }
    }
}

// ---------------------------------------------------------------------------
// Attention tile step (S^T formulation). Ks: K chunk [kv=128][72]; Vt: V^T
// [d=64][136]. S^T = K·Q^T via 16x16x32 (A=K-frag, B=Q-frag); C-layout of
// S^T (kv=fh*4+r, q=fl) IS the B-frag layout of 16x16x16 MFMA, so P^T feeds
// O^T = V^T·P^T straight from registers — no LDS round-trip.
// ---------------------------------------------------------------------------
__device__ __forceinline__ void attn_tile(const _Float16 (*Ks)[72],
                                          const _Float16 (*Vt)[136],
                                          const f16x8 qf[2], f32x4 o_acc[4],
                                          float& m_r, float& l_r, int kv0,
                                          int qt, bool do_mask, int fl, int fh) {
  f32x4 s[8];
#pragma unroll
  for (int t = 0; t < 8; ++t) {
    f16x8 kf0 = *(const f16x8*)(&Ks[t * 16 + fl][fh * 8]);
    f16x8 kf1 = *(const f16x8*)(&Ks[t * 16 + fl][32 + fh * 8]);
    f32x4 z = {0.f, 0.f, 0.f, 0.f};
    z = __builtin_amdgcn_mfma_f32_16x16x32_f16(kf0, qf[0], z, 0, 0, 0);
    z = __builtin_amdgcn_mfma_f32_16x16x32_f16(kf1, qf[1], z, 0, 0, 0);
    s[t] = z;
  }
  const int qg = qt + fl;
  if (do_mask) {
#pragma unroll
    for (int t = 0; t < 8; ++t)
#pragma unroll
      for (int r = 0; r < 4; ++r)
        if (kv0 + t * 16 + fh * 4 + r > qg) s[t][r] = NEG_BIG;
  }
  float mx = s[0][0];
#pragma unroll
  for (int t = 0; t < 8; ++t)
#pragma unroll
    for (int r = 0; r < 4; ++r) mx = fmaxf(mx, s[t][r]);
  mx = fmaxf(mx, __shfl_xor(mx, 16, 64));
  mx = fmaxf(mx, __shfl_xor(mx, 32, 64));
  const float mn = fmaxf(m_r, mx);
  const float a = __expf(m_r - mn);
  float rs = 0.f;
  f16x4 pb[8];
#pragma unroll
  for (int t = 0; t < 8; ++t) {
    float p0 = __expf(s[t][0] - mn);
    float p1 = __expf(s[t][1] - mn);
    float p2 = __expf(s[t][2] - mn);
    float p3 = __expf(s[t][3] - mn);
    rs += (p0 + p1) + (p2 + p3);
    f16x4 pk = {(_Float16)p0, (_Float16)p1, (_Float16)p2, (_Float16)p3};
    pb[t] = pk;
  }
  rs += __shfl_xor(rs, 16, 64);
  rs += __shfl_xor(rs, 32, 64);
  l_r = l_r * a + rs;
  m_r = mn;
#pragma unroll
  for (int mt = 0; mt < 4; ++mt)
#pragma unroll
    for (int r = 0; r < 4; ++r) o_acc[mt][r] *= a;
#pragma unroll
  for (int mt = 0; mt < 4; ++mt)
#pragma unroll
    for (int t = 0; t < 8; ++t) {
      f16x4 va = *(const f16x4*)(&Vt[mt * 16 + fl][t * 16 + fh * 4]);
      o_acc[mt] = __builtin_amdgcn_mfma_f32_16x16x16f16(va, pb[t], o_acc[mt], 0, 0, 0);
    }
}

// ---------------------------------------------------------------------------
// Flash attention, causal, diagonally paired: block p handles q-stripes p and
// 15-p (constant 17 compute-units/block, no tail; KV chunk staged once for
// both). 512 thr = 8 waves, 16 q/wave/stripe. LDS 35.8 KB. Grid (8, 32).
// ---------------------------------------------------------------------------
__global__ __launch_bounds__(512) void attn_kernel(const _Float16* __restrict__ Q,
                                                   const _Float16* __restrict__ K,
                                                   const _Float16* __restrict__ V,
                                                   _Float16* __restrict__ O) {
  __shared__ _Float16 Ks[128][72];     // [kv][d]
  __shared__ _Float16 Vt[64][136];     // [d][kv]

  const int tid = threadIdx.x;
  const int lane = tid & 63;
  const int fl = lane & 15, fh = lane >> 4;
  const int wave = tid >> 6;
  const int bh = blockIdx.y;
  const int b = bh >> 4, h = bh & 15;
  const int p = blockIdx.x;                 // 0..7
  const int qt_lo = p * 128 + wave * 16;
  const int qt_hi = (15 - p) * 128 + wave * 16;

  const _Float16* Qb = Q + (size_t)b * SEQ * DM + h * HD;
  const _Float16* Kb = K + (size_t)b * SEQ * DM + h * HD;
  const _Float16* Vb = V + (size_t)b * SEQ * DM + h * HD;

  const _Float16 hs = (_Float16)0.03125f;  // 1/sqrt(1024), exact in fp16
  f16x8 qlo[2], qhi[2];
#pragma unroll
  for (int kh = 0; kh < 2; ++kh) {
    qlo[kh] = *(const f16x8*)(Qb + (size_t)(qt_lo + fl) * DM + kh * 32 + fh * 8);
    qhi[kh] = *(const f16x8*)(Qb + (size_t)(qt_hi + fl) * DM + kh * 32 + fh * 8);
#pragma unroll
    for (int j = 0; j < 8; ++j) { qlo[kh][j] *= hs; qhi[kh][j] *= hs; }
  }

  f32x4 o_lo[4] = {}, o_hi[4] = {};
  float m_lo = NEG_BIG, l_lo = 0.f, m_hi = NEG_BIG, l_hi = 0.f;

  const int sr = tid >> 3, e = tid & 7, sc8 = e * 8;
  const int cmax = 15 - p;

  for (int c = 0; c <= cmax; ++c) {
    const int kv0 = c * 128;
    f16x8 k0v = *(const f16x8*)(Kb + (size_t)(kv0 + sr) * DM + sc8);
    f16x8 k1v = *(const f16x8*)(Kb + (size_t)(kv0 + 64 + sr) * DM + sc8);
    f16x8 v0v = *(const f16x8*)(Vb + (size_t)(kv0 + sr) * DM + sc8);
    f16x8 v1v = *(const f16x8*)(Vb + (size_t)(kv0 + 64 + sr) * DM + sc8);
    __syncthreads();
    *(f16x8*)(&Ks[sr][sc8]) = k0v;
    *(f16x8*)(&Ks[64 + sr][sc8]) = k1v;
#pragma unroll
    for (int t = 0; t < 8; ++t) {
      const int jj = (t + e) & 7;     // staggered: conflict-free banks
      Vt[sc8 + jj][sr] = v0v[jj];
      Vt[sc8 + jj][64 + sr] = v1v[jj];
    }
    __syncthreads();

    attn_tile(Ks, Vt, qhi, o_hi, m_hi, l_hi, kv0, qt_hi, c == cmax, fl, fh);
    if (c <= p)
      attn_tile(Ks, Vt, qlo, o_lo, m_lo, l_lo, kv0, qt_lo, c == p, fl, fh);
  }

  // epilogue: O[q][d] from O^T C-layout (d = mt*16 + fh*4 + r contiguous in r)
  {
    const float il = 1.0f / l_lo;
    _Float16* Op = O + ((size_t)b * SEQ + qt_lo + fl) * DM + h * HD;
#pragma unroll
    for (int mt = 0; mt < 4; ++mt) {
      f16x4 ov = {(_Float16)(o_lo[mt][0] * il), (_Float16)(o_lo[mt][1] * il),
                  (_Float16)(o_lo[mt][2] * il), (_Float16)(o_lo[mt][3] * il)};
      *(f16x4*)(Op + mt * 16 + fh * 4) = ov;
    }
  }
  {
    const float il = 1.0f / l_hi;
    _Float16* Op = O + ((size_t)b * SEQ + qt_hi + fl) * DM + h * HD;
#pragma unroll
    for (int mt = 0; mt < 4; ++mt) {
      f16x4 ov = {(_Float16)(o_hi[mt][0] * il), (_Float16)(o_hi[mt][1] * il),
                  (_Float16)(o_hi[mt][2] * il), (_Float16)(o_hi[mt][3] * il)};
      *(f16x4*)(Op + mt * 16 + fh * 4) = ov;
    }
  }
}

// ---------------------------------------------------------------------------
extern "C" void kernel_launch(void* const* d_in, const int* in_sizes, int n_in,
                              void* d_out, int out_size, void* d_ws, size_t ws_size,
                              hipStream_t stream) {
  const float* x = (const float*)d_in[0];
  const float* qw = (const float*)d_in[1];
  const float* kw = (const float*)d_in[2];
  const float* vw = (const float*)d_in[3];
  const float* ow = (const float*)d_in[4];
  float* out = (float*)d_out;

  const size_t MD = (size_t)MTOT * DM;  // 4M elements
  _Float16* x16 = (_Float16*)d_ws;      // [0, 4M) ; later reused as attention M
  _Float16* wT = x16 + MD;              // [4M, 8M): qwT,kwT,vwT,owT
  _Float16* Qw = wT + 4 * (size_t)DM * DM;  // [8M, 12M)
  _Float16* Kw = Qw + MD;               // [12M, 16M)
  _Float16* Vw = Kw + MD;               // [16M, 20M)
  _Float16* Mw = x16;                   // attention output reuses x16

  convert_x<<<MD / (256 * 8), 256, 0, stream>>>(x, x16);
  transpose_w<<<dim3(16, 16, 4), 256, 0, stream>>>(qw, kw, vw, ow, wT);

  // Fused QKV (N = 3072) with RoPE applied to Q,K in the epilogue
  gemm128<true, false, true><<<dim3(24, MTOT / 128), 256, 0, stream>>>(x16, wT, Qw, MTOT, DM);

  attn_kernel<<<dim3(8, 32), 512, 0, stream>>>(Qw, Kw, Vw, Mw);

  gemm128<false, true, false><<<dim3(8, MTOT / 128), 256, 0, stream>>>(
      Mw, wT + 3 * (size_t)DM * DM, out, MTOT, DM);
}

// Round 11
// 215.540 us; speedup vs baseline: 1.3894x; 1.0069x over previous
//
#include <hip/hip_runtime.h>
#include <math.h>

typedef _Float16 f16x8 __attribute__((ext_vector_type(8)));
typedef _Float16 f16x4 __attribute__((ext_vector_type(4)));
typedef float f32x4 __attribute__((ext_vector_type(4)));

#define SEQ 2048
#define DM 1024
#define NH 16
#define HD 64
#define MTOT 4096   // batch*seq

#define NEG_BIG (-30000.0f)

__device__ __forceinline__ void gl_lds16(const _Float16* g, _Float16* l) {
  __builtin_amdgcn_global_load_lds(
      (const __attribute__((address_space(1))) unsigned int*)g,
      (__attribute__((address_space(3))) unsigned int*)l, 16, 0, 0);
}

// ---------------------------------------------------------------------------
// prep: z<4 -> transpose+convert weight mat z (fp32 [k][n] -> fp16 [n][k]);
//       z>=4 -> convert x fp32->fp16 (chunk = (z-4)*256 + y*16 + x, 8192 el).
// grid (16,16,6), 256 thr.
// ---------------------------------------------------------------------------
__global__ __launch_bounds__(256) void prep(const float* __restrict__ x,
                                            const float* __restrict__ qw,
                                            const float* __restrict__ kw,
                                            const float* __restrict__ vw,
                                            const float* __restrict__ ow,
                                            _Float16* __restrict__ x16,
                                            _Float16* __restrict__ wT) {
  const int z = blockIdx.z;
  const int t = threadIdx.x;
  if (z >= 4) {
    const int c = (z - 4) * 256 + blockIdx.y * 16 + blockIdx.x;
    const size_t base = (size_t)c * 8192;
#pragma unroll
    for (int rnd = 0; rnd < 4; ++rnd) {
      const size_t i = base + rnd * 2048 + t * 8;
      f32x4 a = *(const f32x4*)(x + i);
      f32x4 b = *(const f32x4*)(x + i + 4);
      f16x8 o;
#pragma unroll
      for (int j = 0; j < 4; ++j) { o[j] = (_Float16)a[j]; o[4 + j] = (_Float16)b[j]; }
      *(f16x8*)(x16 + i) = o;
    }
    return;
  }
  __shared__ float Ts[64][65];
  const float* srcs[4] = {qw, kw, vw, ow};
  const float* src = srcs[z];
  _Float16* dst = wT + (size_t)z * DM * DM;
  const int k0 = blockIdx.y * 64, n0 = blockIdx.x * 64;
  const int r = t >> 2, c4 = (t & 3) * 16;
  const float* sp = src + (size_t)(k0 + r) * DM + n0 + c4;
#pragma unroll
  for (int j = 0; j < 4; ++j) {
    f32x4 vv = *(const f32x4*)(sp + j * 4);
#pragma unroll
    for (int e = 0; e < 4; ++e) Ts[r][c4 + j * 4 + e] = vv[e];
  }
  __syncthreads();
  f16x8 o0, o1;
#pragma unroll
  for (int j = 0; j < 8; ++j) {
    o0[j] = (_Float16)Ts[c4 + j][r];
    o1[j] = (_Float16)Ts[c4 + 8 + j][r];
  }
  _Float16* dp = dst + (size_t)(n0 + r) * DM + k0 + c4;
  *(f16x8*)(dp) = o0;
  *(f16x8*)(dp + 8) = o1;
}

// ---------------------------------------------------------------------------
// Generic GEMM: Y = A(M,K) @ BT^T, BT fp16 [n][k]. Tile BM x BN, BK=64
// (32 MFMA between barriers/wave — AITER cadence), 2x2 waves, unpadded LDS,
// gl_lds16 staging. FUSED3: BT = 3 concatenated mats. ROPE on mats 0,1.
// ---------------------------------------------------------------------------
template <int BM, int BN, bool FUSED3, bool OUTF32, bool ROPE>
__global__ __launch_bounds__(256) void gemm_t(const _Float16* __restrict__ A,
                                              const _Float16* __restrict__ BT,
                                              void* __restrict__ Yv,
                                              int M, int K) {
  constexpr int WM = BM / 2, WN = BN / 2;
  constexpr int MI = WM / 16, NI = WN / 16;
  __shared__ _Float16 As[BM * 64];
  __shared__ _Float16 Bs[BN * 64];
  const int tid = threadIdx.x;
  const int lane = tid & 63;
  const int fl = lane & 15, fh = lane >> 4;
  const int wave = tid >> 6;
  const int m0 = blockIdx.y * BM;
  int n0 = blockIdx.x * BN;
  int mat = 0;
  const _Float16* Bp = BT;
  char* Yp = (char*)Yv;
  if (FUSED3) {
    mat = n0 >> 10;
    n0 &= 1023;
    Bp = BT + (size_t)mat * DM * DM;
    Yp += (size_t)mat * M * DM * (OUTF32 ? 4 : 2);
  }
  const int wm = (wave >> 1) * WM, wn = (wave & 1) * WN;

  // staging: each gl_lds16 covers 8 rows (64 lanes x 16B / 128B row)
  const int srow = lane >> 3, scol = (lane & 7) * 8;

  f32x4 acc[MI][NI] = {};

  for (int k0 = 0; k0 < K; k0 += 64) {
    __syncthreads();
#pragma unroll
    for (int j = 0; j < BM / 32; ++j) {
      const int rb = wave * 8 + j * 32;
      gl_lds16(A + (size_t)(m0 + rb + srow) * K + k0 + scol, &As[rb * 64]);
    }
#pragma unroll
    for (int j = 0; j < BN / 32; ++j) {
      const int rb = wave * 8 + j * 32;
      gl_lds16(Bp + (size_t)(n0 + rb + srow) * K + k0 + scol, &Bs[rb * 64]);
    }
    __syncthreads();
#pragma unroll
    for (int kh = 0; kh < 2; ++kh) {
      f16x8 af[MI], bf[NI];
#pragma unroll
      for (int mi = 0; mi < MI; ++mi)
        af[mi] = *(const f16x8*)(&As[(wm + mi * 16 + fl) * 64 + kh * 32 + fh * 8]);
#pragma unroll
      for (int ni = 0; ni < NI; ++ni)
        bf[ni] = *(const f16x8*)(&Bs[(wn + ni * 16 + fl) * 64 + kh * 32 + fh * 8]);
#pragma unroll
      for (int mi = 0; mi < MI; ++mi)
#pragma unroll
        for (int ni = 0; ni < NI; ++ni)
          acc[mi][ni] = __builtin_amdgcn_mfma_f32_16x16x32_f16(af[mi], bf[ni], acc[mi][ni], 0, 0, 0);
    }
  }

  // C/D: row = fh*4 + r, col = fl
#pragma unroll
  for (int mi = 0; mi < MI; ++mi)
#pragma unroll
    for (int ni = 0; ni < NI; ++ni) {
      const int gm = m0 + wm + mi * 16 + fh * 4;
      const int gn = n0 + wn + ni * 16 + fl;
      if (ROPE && mat < 2) {
        const int d2 = (gn & 63) >> 1;
        const float inv = __powf(10000.0f, -(float)d2 * (1.0f / 32.0f));
        const float sgn = (gn & 1) ? 1.0f : -1.0f;
#pragma unroll
        for (int r = 0; r < 4; ++r) {
          const int s = (gm + r) & (SEQ - 1);
          float c, sn;
          __sincosf((float)s * inv, &sn, &c);
          const float v = acc[mi][ni][r];
          const float p = __shfl_xor(v, 1, 64);
          acc[mi][ni][r] = v * c + sgn * p * sn;
        }
      }
#pragma unroll
      for (int r = 0; r < 4; ++r) {
        if (OUTF32)
          ((float*)Yp)[(size_t)(gm + r) * DM + gn] = acc[mi][ni][r];
        else
          ((_Float16*)Yp)[(size_t)(gm + r) * DM + gn] = (_Float16)acc[mi][ni][r];
      }
    }
}

// ---------------------------------------------------------------------------
// Attention tile step (S^T formulation). S^T = K·Q^T via 16x16x32; C-layout
// of S^T (kv=fh*4+r, q=fl) IS the B-frag layout of 16x16x16 MFMA, so P^T
// feeds O^T = V^T·P^T straight from registers — no LDS round-trip.
// ---------------------------------------------------------------------------
__device__ __forceinline__ void attn_tile(const _Float16 (*Ks)[72],
                                          const _Float16 (*Vt)[136],
                                          const f16x8 qf[2], f32x4 o_acc[4],
                                          float& m_r, float& l_r, int kv0,
                                          int qt, bool do_mask, int fl, int fh) {
  f32x4 s[8];
#pragma unroll
  for (int t = 0; t < 8; ++t) {
    f16x8 kf0 = *(const f16x8*)(&Ks[t * 16 + fl][fh * 8]);
    f16x8 kf1 = *(const f16x8*)(&Ks[t * 16 + fl][32 + fh * 8]);
    f32x4 z = {0.f, 0.f, 0.f, 0.f};
    z = __builtin_amdgcn_mfma_f32_16x16x32_f16(kf0, qf[0], z, 0, 0, 0);
    z = __builtin_amdgcn_mfma_f32_16x16x32_f16(kf1, qf[1], z, 0, 0, 0);
    s[t] = z;
  }
  const int qg = qt + fl;
  if (do_mask) {
#pragma unroll
    for (int t = 0; t < 8; ++t)
#pragma unroll
      for (int r = 0; r < 4; ++r)
        if (kv0 + t * 16 + fh * 4 + r > qg) s[t][r] = NEG_BIG;
  }
  float mx = s[0][0];
#pragma unroll
  for (int t = 0; t < 8; ++t)
#pragma unroll
    for (int r = 0; r < 4; ++r) mx = fmaxf(mx, s[t][r]);
  mx = fmaxf(mx, __shfl_xor(mx, 16, 64));
  mx = fmaxf(mx, __shfl_xor(mx, 32, 64));
  const float mn = fmaxf(m_r, mx);
  const float a = __expf(m_r - mn);
  float rs = 0.f;
  f16x4 pb[8];
#pragma unroll
  for (int t = 0; t < 8; ++t) {
    float p0 = __expf(s[t][0] - mn);
    float p1 = __expf(s[t][1] - mn);
    float p2 = __expf(s[t][2] - mn);
    float p3 = __expf(s[t][3] - mn);
    rs += (p0 + p1) + (p2 + p3);
    f16x4 pk = {(_Float16)p0, (_Float16)p1, (_Float16)p2, (_Float16)p3};
    pb[t] = pk;
  }
  rs += __shfl_xor(rs, 16, 64);
  rs += __shfl_xor(rs, 32, 64);
  l_r = l_r * a + rs;
  m_r = mn;
#pragma unroll
  for (int mt = 0; mt < 4; ++mt)
#pragma unroll
    for (int r = 0; r < 4; ++r) o_acc[mt][r] *= a;
#pragma unroll
  for (int mt = 0; mt < 4; ++mt)
#pragma unroll
    for (int t = 0; t < 8; ++t) {
      f16x4 va = *(const f16x4*)(&Vt[mt * 16 + fl][t * 16 + fh * 4]);
      o_acc[mt] = __builtin_amdgcn_mfma_f32_16x16x16f16(va, pb[t], o_acc[mt], 0, 0, 0);
    }
}

// ---------------------------------------------------------------------------
// Flash attention, causal, diagonally paired: block p handles q-stripes p and
// 15-p (constant 17 compute-units/block, no tail; KV chunk staged once for
// both). 512 thr = 8 waves, 16 q/wave/stripe. LDS 35.8 KB. Grid (8, 32).
// ---------------------------------------------------------------------------
__global__ __launch_bounds__(512) void attn_kernel(const _Float16* __restrict__ Q,
                                                   const _Float16* __restrict__ K,
                                                   const _Float16* __restrict__ V,
                                                   _Float16* __restrict__ O) {
  __shared__ _Float16 Ks[128][72];     // [kv][d]
  __shared__ _Float16 Vt[64][136];     // [d][kv]

  const int tid = threadIdx.x;
  const int lane = tid & 63;
  const int fl = lane & 15, fh = lane >> 4;
  const int wave = tid >> 6;
  const int bh = blockIdx.y;
  const int b = bh >> 4, h = bh & 15;
  const int p = blockIdx.x;                 // 0..7
  const int qt_lo = p * 128 + wave * 16;
  const int qt_hi = (15 - p) * 128 + wave * 16;

  const _Float16* Qb = Q + (size_t)b * SEQ * DM + h * HD;
  const _Float16* Kb = K + (size_t)b * SEQ * DM + h * HD;
  const _Float16* Vb = V + (size_t)b * SEQ * DM + h * HD;

  const _Float16 hs = (_Float16)0.03125f;  // 1/sqrt(1024), exact in fp16
  f16x8 qlo[2], qhi[2];
#pragma unroll
  for (int kh = 0; kh < 2; ++kh) {
    qlo[kh] = *(const f16x8*)(Qb + (size_t)(qt_lo + fl) * DM + kh * 32 + fh * 8);
    qhi[kh] = *(const f16x8*)(Qb + (size_t)(qt_hi + fl) * DM + kh * 32 + fh * 8);
#pragma unroll
    for (int j = 0; j < 8; ++j) { qlo[kh][j] *= hs; qhi[kh][j] *= hs; }
  }

  f32x4 o_lo[4] = {}, o_hi[4] = {};
  float m_lo = NEG_BIG, l_lo = 0.f, m_hi = NEG_BIG, l_hi = 0.f;

  const int sr = tid >> 3, e = tid & 7, sc8 = e * 8;
  const int cmax = 15 - p;

  for (int c = 0; c <= cmax; ++c) {
    const int kv0 = c * 128;
    f16x8 k0v = *(const f16x8*)(Kb + (size_t)(kv0 + sr) * DM + sc8);
    f16x8 k1v = *(const f16x8*)(Kb + (size_t)(kv0 + 64 + sr) * DM + sc8);
    f16x8 v0v = *(const f16x8*)(Vb + (size_t)(kv0 + sr) * DM + sc8);
    f16x8 v1v = *(const f16x8*)(Vb + (size_t)(kv0 + 64 + sr) * DM + sc8);
    __syncthreads();
    *(f16x8*)(&Ks[sr][sc8]) = k0v;
    *(f16x8*)(&Ks[64 + sr][sc8]) = k1v;
#pragma unroll
    for (int t = 0; t < 8; ++t) {
      const int jj = (t + e) & 7;     // staggered: conflict-free banks
      Vt[sc8 + jj][sr] = v0v[jj];
      Vt[sc8 + jj][64 + sr] = v1v[jj];
    }
    __syncthreads();

    attn_tile(Ks, Vt, qhi, o_hi, m_hi, l_hi, kv0, qt_hi, c == cmax, fl, fh);
    if (c <= p)
      attn_tile(Ks, Vt, qlo, o_lo, m_lo, l_lo, kv0, qt_lo, c == p, fl, fh);
  }

  // epilogue: O[q][d] from O^T C-layout (d = mt*16 + fh*4 + r contiguous in r)
  {
    const float il = 1.0f / l_lo;
    _Float16* Op = O + ((size_t)b * SEQ + qt_lo + fl) * DM + h * HD;
#pragma unroll
    for (int mt = 0; mt < 4; ++mt) {
      f16x4 ov = {(_Float16)(o_lo[mt][0] * il), (_Float16)(o_lo[mt][1] * il),
                  (_Float16)(o_lo[mt][2] * il), (_Float16)(o_lo[mt][3] * il)};
      *(f16x4*)(Op + mt * 16 + fh * 4) = ov;
    }
  }
  {
    const float il = 1.0f / l_hi;
    _Float16* Op = O + ((size_t)b * SEQ + qt_hi + fl) * DM + h * HD;
#pragma unroll
    for (int mt = 0; mt < 4; ++mt) {
      f16x4 ov = {(_Float16)(o_hi[mt][0] * il), (_Float16)(o_hi[mt][1] * il),
                  (_Float16)(o_hi[mt][2] * il), (_Float16)(o_hi[mt][3] * il)};
      *(f16x4*)(Op + mt * 16 + fh * 4) = ov;
    }
  }
}

// ---------------------------------------------------------------------------
extern "C" void kernel_launch(void* const* d_in, const int* in_sizes, int n_in,
                              void* d_out, int out_size, void* d_ws, size_t ws_size,
                              hipStream_t stream) {
  const float* x = (const float*)d_in[0];
  const float* qw = (const float*)d_in[1];
  const float* kw = (const float*)d_in[2];
  const float* vw = (const float*)d_in[3];
  const float* ow = (const float*)d_in[4];
  float* out = (float*)d_out;

  const size_t MD = (size_t)MTOT * DM;  // 4M elements
  _Float16* x16 = (_Float16*)d_ws;      // [0, 4M) ; later reused as attention M
  _Float16* wT = x16 + MD;              // [4M, 8M): qwT,kwT,vwT,owT
  _Float16* Qw = wT + 4 * (size_t)DM * DM;  // [8M, 12M)
  _Float16* Kw = Qw + MD;               // [12M, 16M)
  _Float16* Vw = Kw + MD;               // [16M, 20M)
  _Float16* Mw = x16;                   // attention output reuses x16

  prep<<<dim3(16, 16, 6), 256, 0, stream>>>(x, qw, kw, vw, ow, x16, wT);

  // Fused QKV (N = 3072) with RoPE applied to Q,K in the epilogue
  gemm_t<128, 128, true, false, true><<<dim3(24, MTOT / 128), 256, 0, stream>>>(
      x16, wT, Qw, MTOT, DM);

  attn_kernel<<<dim3(8, 32), 512, 0, stream>>>(Qw, Kw, Vw, Mw);

  // Out projection: 64x128 tiles -> 512 blocks (2/CU)
  gemm_t<64, 128, false, true, false><<<dim3(8, MTOT / 64), 256, 0, stream>>>(
      Mw, wT + 3 * (size_t)DM * DM, out, MTOT, DM);
}

// Round 12
// 197.042 us; speedup vs baseline: 1.5198x; 1.0939x over previous
//
#include <hip/hip_runtime.h>
#include <math.h>

typedef _Float16 f16x8 __attribute__((ext_vector_type(8)));
typedef _Float16 f16x4 __attribute__((ext_vector_type(4)));
typedef float f32x4 __attribute__((ext_vector_type(4)));

#define SEQ 2048
#define DM 1024
#define NH 16
#define HD 64
#define MTOT 4096   // batch*seq

#define NEG_BIG (-30000.0f)

__device__ __forceinline__ void gl_lds16(const _Float16* g, _Float16* l) {
  __builtin_amdgcn_global_load_lds(
      (const __attribute__((address_space(1))) unsigned int*)g,
      (__attribute__((address_space(3))) unsigned int*)l, 16, 0, 0);
}

// ---------------------------------------------------------------------------
// prep: z<4 -> transpose+convert weight mat z (fp32 [k][n] -> fp16 [n][k]);
//       z>=4 -> convert x fp32->fp16 (chunk = (z-4)*256 + y*16 + x, 8192 el).
// grid (16,16,6), 256 thr.
// ---------------------------------------------------------------------------
__global__ __launch_bounds__(256) void prep(const float* __restrict__ x,
                                            const float* __restrict__ qw,
                                            const float* __restrict__ kw,
                                            const float* __restrict__ vw,
                                            const float* __restrict__ ow,
                                            _Float16* __restrict__ x16,
                                            _Float16* __restrict__ wT) {
  const int z = blockIdx.z;
  const int t = threadIdx.x;
  if (z >= 4) {
    const int c = (z - 4) * 256 + blockIdx.y * 16 + blockIdx.x;
    const size_t base = (size_t)c * 8192;
#pragma unroll
    for (int rnd = 0; rnd < 4; ++rnd) {
      const size_t i = base + rnd * 2048 + t * 8;
      f32x4 a = *(const f32x4*)(x + i);
      f32x4 b = *(const f32x4*)(x + i + 4);
      f16x8 o;
#pragma unroll
      for (int j = 0; j < 4; ++j) { o[j] = (_Float16)a[j]; o[4 + j] = (_Float16)b[j]; }
      *(f16x8*)(x16 + i) = o;
    }
    return;
  }
  __shared__ float Ts[64][65];
  const float* srcs[4] = {qw, kw, vw, ow};
  const float* src = srcs[z];
  _Float16* dst = wT + (size_t)z * DM * DM;
  const int k0 = blockIdx.y * 64, n0 = blockIdx.x * 64;
  const int r = t >> 2, c4 = (t & 3) * 16;
  const float* sp = src + (size_t)(k0 + r) * DM + n0 + c4;
#pragma unroll
  for (int j = 0; j < 4; ++j) {
    f32x4 vv = *(const f32x4*)(sp + j * 4);
#pragma unroll
    for (int e = 0; e < 4; ++e) Ts[r][c4 + j * 4 + e] = vv[e];
  }
  __syncthreads();
  f16x8 o0, o1;
#pragma unroll
  for (int j = 0; j < 8; ++j) {
    o0[j] = (_Float16)Ts[c4 + j][r];
    o1[j] = (_Float16)Ts[c4 + 8 + j][r];
  }
  _Float16* dp = dst + (size_t)(n0 + r) * DM + k0 + c4;
  *(f16x8*)(dp) = o0;
  *(f16x8*)(dp + 8) = o1;
}

// ---------------------------------------------------------------------------
// Generic GEMM (m97 structure, BK=32): Y = A(M,K) @ BT^T, BT fp16 [n][k].
// Tile BM x BN, 2x2 waves, UNPADDED [rows][32] LDS (64-B row: conflict-free
// for the b128 fragment reads), gl_lds16 staging in 16-row groups.
// NOTE: BK=64 (128-B rows) puts all fl-lanes in one 4-bank window — 3x the
// conflicts, MfmaUtil 18.7->13.5% (measured round 11). Keep BK=32.
// FUSED3: BT = 3 concatenated mats. ROPE on mats 0,1.
// ---------------------------------------------------------------------------
template <int BM, int BN, bool FUSED3, bool OUTF32, bool ROPE>
__global__ __launch_bounds__(256) void gemm_t(const _Float16* __restrict__ A,
                                              const _Float16* __restrict__ BT,
                                              void* __restrict__ Yv,
                                              int M, int K) {
  constexpr int WM = BM / 2, WN = BN / 2;
  constexpr int MI = WM / 16, NI = WN / 16;
  __shared__ _Float16 As[BM * 32];
  __shared__ _Float16 Bs[BN * 32];
  const int tid = threadIdx.x;
  const int lane = tid & 63;
  const int fl = lane & 15, fh = lane >> 4;
  const int wave = tid >> 6;
  const int m0 = blockIdx.y * BM;
  int n0 = blockIdx.x * BN;
  int mat = 0;
  const _Float16* Bp = BT;
  char* Yp = (char*)Yv;
  if (FUSED3) {
    mat = n0 >> 10;
    n0 &= 1023;
    Bp = BT + (size_t)mat * DM * DM;
    Yp += (size_t)mat * M * DM * (OUTF32 ? 4 : 2);
  }
  const int wm = (wave >> 1) * WM, wn = (wave & 1) * WN;

  // staging: one gl_lds16 covers 16 rows (64 lanes x 16B / 64B row)
  const int l4 = lane >> 2, lc = (lane & 3) * 8;

  f32x4 acc[MI][NI] = {};

  for (int k0 = 0; k0 < K; k0 += 32) {
    __syncthreads();
#pragma unroll
    for (int j = wave; j < BM / 16; j += 4)
      gl_lds16(A + (size_t)(m0 + j * 16 + l4) * K + k0 + lc, &As[j * 16 * 32]);
#pragma unroll
    for (int j = wave; j < BN / 16; j += 4)
      gl_lds16(Bp + (size_t)(n0 + j * 16 + l4) * K + k0 + lc, &Bs[j * 16 * 32]);
    __syncthreads();
    f16x8 af[MI], bf[NI];
#pragma unroll
    for (int mi = 0; mi < MI; ++mi)
      af[mi] = *(const f16x8*)(&As[(wm + mi * 16 + fl) * 32 + fh * 8]);
#pragma unroll
    for (int ni = 0; ni < NI; ++ni)
      bf[ni] = *(const f16x8*)(&Bs[(wn + ni * 16 + fl) * 32 + fh * 8]);
#pragma unroll
    for (int mi = 0; mi < MI; ++mi)
#pragma unroll
      for (int ni = 0; ni < NI; ++ni)
        acc[mi][ni] = __builtin_amdgcn_mfma_f32_16x16x32_f16(af[mi], bf[ni], acc[mi][ni], 0, 0, 0);
  }

  // C/D: row = fh*4 + r, col = fl
#pragma unroll
  for (int mi = 0; mi < MI; ++mi)
#pragma unroll
    for (int ni = 0; ni < NI; ++ni) {
      const int gm = m0 + wm + mi * 16 + fh * 4;
      const int gn = n0 + wn + ni * 16 + fl;
      if (ROPE && mat < 2) {
        const int d2 = (gn & 63) >> 1;
        const float inv = __powf(10000.0f, -(float)d2 * (1.0f / 32.0f));
        const float sgn = (gn & 1) ? 1.0f : -1.0f;
#pragma unroll
        for (int r = 0; r < 4; ++r) {
          const int s = (gm + r) & (SEQ - 1);
          float c, sn;
          __sincosf((float)s * inv, &sn, &c);
          const float v = acc[mi][ni][r];
          const float p = __shfl_xor(v, 1, 64);
          acc[mi][ni][r] = v * c + sgn * p * sn;
        }
      }
#pragma unroll
      for (int r = 0; r < 4; ++r) {
        if (OUTF32)
          ((float*)Yp)[(size_t)(gm + r) * DM + gn] = acc[mi][ni][r];
        else
          ((_Float16*)Yp)[(size_t)(gm + r) * DM + gn] = (_Float16)acc[mi][ni][r];
      }
    }
}

// ---------------------------------------------------------------------------
// Attention tile step (S^T formulation). S^T = K·Q^T via 16x16x32; C-layout
// of S^T (kv=fh*4+r, q=fl) IS the B-frag layout of 16x16x16 MFMA, so P^T
// feeds O^T = V^T·P^T straight from registers — no LDS round-trip.
// ---------------------------------------------------------------------------
__device__ __forceinline__ void attn_tile(const _Float16 (*Ks)[72],
                                          const _Float16 (*Vt)[136],
                                          const f16x8 qf[2], f32x4 o_acc[4],
                                          float& m_r, float& l_r, int kv0,
                                          int qt, bool do_mask, int fl, int fh) {
  f32x4 s[8];
#pragma unroll
  for (int t = 0; t < 8; ++t) {
    f16x8 kf0 = *(const f16x8*)(&Ks[t * 16 + fl][fh * 8]);
    f16x8 kf1 = *(const f16x8*)(&Ks[t * 16 + fl][32 + fh * 8]);
    f32x4 z = {0.f, 0.f, 0.f, 0.f};
    z = __builtin_amdgcn_mfma_f32_16x16x32_f16(kf0, qf[0], z, 0, 0, 0);
    z = __builtin_amdgcn_mfma_f32_16x16x32_f16(kf1, qf[1], z, 0, 0, 0);
    s[t] = z;
  }
  const int qg = qt + fl;
  if (do_mask) {
#pragma unroll
    for (int t = 0; t < 8; ++t)
#pragma unroll
      for (int r = 0; r < 4; ++r)
        if (kv0 + t * 16 + fh * 4 + r > qg) s[t][r] = NEG_BIG;
  }
  float mx = s[0][0];
#pragma unroll
  for (int t = 0; t < 8; ++t)
#pragma unroll
    for (int r = 0; r < 4; ++r) mx = fmaxf(mx, s[t][r]);
  mx = fmaxf(mx, __shfl_xor(mx, 16, 64));
  mx = fmaxf(mx, __shfl_xor(mx, 32, 64));
  const float mn = fmaxf(m_r, mx);
  const float a = __expf(m_r - mn);
  float rs = 0.f;
  f16x4 pb[8];
#pragma unroll
  for (int t = 0; t < 8; ++t) {
    float p0 = __expf(s[t][0] - mn);
    float p1 = __expf(s[t][1] - mn);
    float p2 = __expf(s[t][2] - mn);
    float p3 = __expf(s[t][3] - mn);
    rs += (p0 + p1) + (p2 + p3);
    f16x4 pk = {(_Float16)p0, (_Float16)p1, (_Float16)p2, (_Float16)p3};
    pb[t] = pk;
  }
  rs += __shfl_xor(rs, 16, 64);
  rs += __shfl_xor(rs, 32, 64);
  l_r = l_r * a + rs;
  m_r = mn;
#pragma unroll
  for (int mt = 0; mt < 4; ++mt)
#pragma unroll
    for (int r = 0; r < 4; ++r) o_acc[mt][r] *= a;
#pragma unroll
  for (int mt = 0; mt < 4; ++mt)
#pragma unroll
    for (int t = 0; t < 8; ++t) {
      f16x4 va = *(const f16x4*)(&Vt[mt * 16 + fl][t * 16 + fh * 4]);
      o_acc[mt] = __builtin_amdgcn_mfma_f32_16x16x16f16(va, pb[t], o_acc[mt], 0, 0, 0);
    }
}

// ---------------------------------------------------------------------------
// Flash attention, causal, diagonally paired: block p handles q-stripes p and
// 15-p (constant 17 compute-units/block, no tail; KV chunk staged once for
// both). 512 thr = 8 waves, 16 q/wave/stripe. LDS 35.8 KB. Grid (8, 32).
// ---------------------------------------------------------------------------
__global__ __launch_bounds__(512) void attn_kernel(const _Float16* __restrict__ Q,
                                                   const _Float16* __restrict__ K,
                                                   const _Float16* __restrict__ V,
                                                   _Float16* __restrict__ O) {
  __shared__ _Float16 Ks[128][72];     // [kv][d]
  __shared__ _Float16 Vt[64][136];     // [d][kv]

  const int tid = threadIdx.x;
  const int lane = tid & 63;
  const int fl = lane & 15, fh = lane >> 4;
  const int wave = tid >> 6;
  const int bh = blockIdx.y;
  const int b = bh >> 4, h = bh & 15;
  const int p = blockIdx.x;                 // 0..7
  const int qt_lo = p * 128 + wave * 16;
  const int qt_hi = (15 - p) * 128 + wave * 16;

  const _Float16* Qb = Q + (size_t)b * SEQ * DM + h * HD;
  const _Float16* Kb = K + (size_t)b * SEQ * DM + h * HD;
  const _Float16* Vb = V + (size_t)b * SEQ * DM + h * HD;

  const _Float16 hs = (_Float16)0.03125f;  // 1/sqrt(1024), exact in fp16
  f16x8 qlo[2], qhi[2];
#pragma unroll
  for (int kh = 0; kh < 2; ++kh) {
    qlo[kh] = *(const f16x8*)(Qb + (size_t)(qt_lo + fl) * DM + kh * 32 + fh * 8);
    qhi[kh] = *(const f16x8*)(Qb + (size_t)(qt_hi + fl) * DM + kh * 32 + fh * 8);
#pragma unroll
    for (int j = 0; j < 8; ++j) { qlo[kh][j] *= hs; qhi[kh][j] *= hs; }
  }

  f32x4 o_lo[4] = {}, o_hi[4] = {};
  float m_lo = NEG_BIG, l_lo = 0.f, m_hi = NEG_BIG, l_hi = 0.f;

  const int sr = tid >> 3, e = tid & 7, sc8 = e * 8;
  const int cmax = 15 - p;

  for (int c = 0; c <= cmax; ++c) {
    const int kv0 = c * 128;
    f16x8 k0v = *(const f16x8*)(Kb + (size_t)(kv0 + sr) * DM + sc8);
    f16x8 k1v = *(const f16x8*)(Kb + (size_t)(kv0 + 64 + sr) * DM + sc8);
    f16x8 v0v = *(const f16x8*)(Vb + (size_t)(kv0 + sr) * DM + sc8);
    f16x8 v1v = *(const f16x8*)(Vb + (size_t)(kv0 + 64 + sr) * DM + sc8);
    __syncthreads();
    *(f16x8*)(&Ks[sr][sc8]) = k0v;
    *(f16x8*)(&Ks[64 + sr][sc8]) = k1v;
#pragma unroll
    for (int t = 0; t < 8; ++t) {
      const int jj = (t + e) & 7;     // staggered: conflict-free banks
      Vt[sc8 + jj][sr] = v0v[jj];
      Vt[sc8 + jj][64 + sr] = v1v[jj];
    }
    __syncthreads();

    attn_tile(Ks, Vt, qhi, o_hi, m_hi, l_hi, kv0, qt_hi, c == cmax, fl, fh);
    if (c <= p)
      attn_tile(Ks, Vt, qlo, o_lo, m_lo, l_lo, kv0, qt_lo, c == p, fl, fh);
  }

  // epilogue: O[q][d] from O^T C-layout (d = mt*16 + fh*4 + r contiguous in r)
  {
    const float il = 1.0f / l_lo;
    _Float16* Op = O + ((size_t)b * SEQ + qt_lo + fl) * DM + h * HD;
#pragma unroll
    for (int mt = 0; mt < 4; ++mt) {
      f16x4 ov = {(_Float16)(o_lo[mt][0] * il), (_Float16)(o_lo[mt][1] * il),
                  (_Float16)(o_lo[mt][2] * il), (_Float16)(o_lo[mt][3] * il)};
      *(f16x4*)(Op + mt * 16 + fh * 4) = ov;
    }
  }
  {
    const float il = 1.0f / l_hi;
    _Float16* Op = O + ((size_t)b * SEQ + qt_hi + fl) * DM + h * HD;
#pragma unroll
    for (int mt = 0; mt < 4; ++mt) {
      f16x4 ov = {(_Float16)(o_hi[mt][0] * il), (_Float16)(o_hi[mt][1] * il),
                  (_Float16)(o_hi[mt][2] * il), (_Float16)(o_hi[mt][3] * il)};
      *(f16x4*)(Op + mt * 16 + fh * 4) = ov;
    }
  }
}

// ---------------------------------------------------------------------------
extern "C" void kernel_launch(void* const* d_in, const int* in_sizes, int n_in,
                              void* d_out, int out_size, void* d_ws, size_t ws_size,
                              hipStream_t stream) {
  const float* x = (const float*)d_in[0];
  const float* qw = (const float*)d_in[1];
  const float* kw = (const float*)d_in[2];
  const float* vw = (const float*)d_in[3];
  const float* ow = (const float*)d_in[4];
  float* out = (float*)d_out;

  const size_t MD = (size_t)MTOT * DM;  // 4M elements
  _Float16* x16 = (_Float16*)d_ws;      // [0, 4M) ; later reused as attention M
  _Float16* wT = x16 + MD;              // [4M, 8M): qwT,kwT,vwT,owT
  _Float16* Qw = wT + 4 * (size_t)DM * DM;  // [8M, 12M)
  _Float16* Kw = Qw + MD;               // [12M, 16M)
  _Float16* Vw = Kw + MD;               // [16M, 20M)
  _Float16* Mw = x16;                   // attention output reuses x16

  prep<<<dim3(16, 16, 6), 256, 0, stream>>>(x, qw, kw, vw, ow, x16, wT);

  // Fused QKV (N = 3072) with RoPE applied to Q,K in the epilogue
  gemm_t<128, 128, true, false, true><<<dim3(24, MTOT / 128), 256, 0, stream>>>(
      x16, wT, Qw, MTOT, DM);

  attn_kernel<<<dim3(8, 32), 512, 0, stream>>>(Qw, Kw, Vw, Mw);

  // Out projection: 64x128 tiles -> 512 blocks (2/CU)
  gemm_t<64, 128, false, true, false><<<dim3(8, MTOT / 64), 256, 0, stream>>>(
      Mw, wT + 3 * (size_t)DM * DM, out, MTOT, DM);
}